// Round 6
// baseline (505.056 us; speedup 1.0000x reference)
//
#include <hip/hip_runtime.h>
#include <hip/hip_bf16.h>

// ---------------- types & helpers ----------------

typedef __attribute__((ext_vector_type(8)))  short bf16x8;   // 8 bf16 = 4 VGPR
typedef __attribute__((ext_vector_type(16))) float f32x16;   // MFMA 32x32 acc
typedef unsigned short u16;

__device__ __forceinline__ u16 f2bf(float x) {               // RNE fp32->bf16
  union { float f; unsigned u; } c; c.f = x;
  return (u16)((c.u + 0x7fffu + ((c.u >> 16) & 1u)) >> 16);
}
__device__ __forceinline__ float bf2f(u16 u) {               // exact bf16->fp32
  union { unsigned u; float f; } c; c.u = ((unsigned)u) << 16;
  return c.f;
}

// async global->LDS, 16B per lane; LDS dest = wave-uniform base + lane*16
__device__ __forceinline__ void gld16(const void* g, void* l) {
  __builtin_amdgcn_global_load_lds(
      (const __attribute__((address_space(1))) unsigned int*)g,
      (__attribute__((address_space(3))) unsigned int*)l, 16, 0, 0);
}

// ---------------- sentinel & merged dtype probe ----------------

__global__ void k_sentinel(u16* __restrict__ out, int n) {
  int i = blockIdx.x * blockDim.x + threadIdx.x;
  if (i < n) out[i] = 0x3F00;
}

// block 0: float dtype probe on v; block 1: edge-width probe on ei
__global__ void k_probe(const unsigned* __restrict__ v, int nv, int* __restrict__ vflag,
                        const unsigned* __restrict__ ei, int ne, int* __restrict__ eflag) {
  __shared__ unsigned red[256];
  if (blockIdx.x == 0) {
    int ok = 0;
    for (int i = threadIdx.x; i < nv; i += 256) {
      unsigned lo = v[i] & 0xffffu;
      unsigned ef = (lo >> 7) & 0xffu;
      if (ef >= 115u && ef <= 140u) ok++;
    }
    red[threadIdx.x] = (unsigned)ok;
    __syncthreads();
    for (int s = 128; s > 0; s >>= 1) {
      if (threadIdx.x < s) red[threadIdx.x] += red[threadIdx.x + s];
      __syncthreads();
    }
    if (threadIdx.x == 0) *vflag = ((int)red[0] < nv / 2) ? 1 : 0;
  } else {
    unsigned acc = 0;
    for (int i = threadIdx.x; i < ne; i += 256)
      if (i & 1) acc |= ei[i];
    red[threadIdx.x] = acc;
    __syncthreads();
    for (int s = 128; s > 0; s >>= 1) {
      if (threadIdx.x < s) red[threadIdx.x] |= red[threadIdx.x + s];
      __syncthreads();
    }
    if (threadIdx.x == 0) *eflag = (red[0] == 0u) ? 1 : 0;
  }
}

// ---------------- weight pre-pack ----------------
// Pack W[K][Fo] into fragment-linear slots: slot s = (nt*KS + ks)*8 + fb,
// lane l: element W[ks*32 + (fb&1)*16 + (l>>5)*8 + j][nt*128 + (fb>>1)*32 + (l&31)].
__global__ void k_wpack(const void* __restrict__ W, const int* __restrict__ wflagp,
                        int K, int Fo, u16* __restrict__ dstHi, u16* __restrict__ dstLo) {
  const int t = blockIdx.x * 256 + threadIdx.x;
  const int KS = K >> 5;
  const int total = (Fo >> 7) * KS * 8;
  const int s = t >> 6;
  if (s >= total) return;
  const int lane = t & 63;
  const int fb = s & 7;
  const int sk = s >> 3;
  const int ks = sk % KS;
  const int nt = sk / KS;
  const int col = (nt << 7) + ((fb >> 1) << 5) + (lane & 31);
  const int row = (ks << 5) + ((fb & 1) << 4) + ((lane >> 5) << 3);
  const int wflag = *wflagp;
  bf16x8 hi;
  if (wflag) {
    const float* Wf = (const float*)W;
    bf16x8 lo;
#pragma unroll
    for (int j = 0; j < 8; j++) {
      float wv = Wf[(size_t)(row + j) * Fo + col];
      u16 h = f2bf(wv);
      hi[j] = (short)h;
      lo[j] = (short)f2bf(wv - bf2f(h));
    }
    *(bf16x8*)(dstLo + (size_t)s * 512 + lane * 8) = lo;
  } else {
    const u16* Wb = (const u16*)W;
#pragma unroll
    for (int j = 0; j < 8; j++)
      hi[j] = (short)Wb[(size_t)(row + j) * Fo + col];
  }
  *(bf16x8*)(dstHi + (size_t)s * 512 + lane * 8) = hi;
}

// ---------------- preprocessing ----------------

__global__ void k_zero(float* __restrict__ deg, int* __restrict__ cnt, int n) {
  int i = blockIdx.x * blockDim.x + threadIdx.x;
  if (i < n) { deg[i] = 0.0f; cnt[i] = 0; }
}

__global__ void k_decode(const void* __restrict__ ei, const int* __restrict__ eflag,
                         int E, int N, int* __restrict__ rowi, int* __restrict__ coli,
                         float* __restrict__ deg, int* __restrict__ cnt) {
  int e = blockIdx.x * blockDim.x + threadIdx.x;
  if (e >= E) return;
  int f = *eflag;
  int r, c;
  if (f) {
    const long long* q = (const long long*)ei;
    r = (int)q[e]; c = (int)q[e + E];
  } else {
    const int* q = (const int*)ei;
    r = q[e]; c = q[e + E];
  }
  r = min(max(r, 0), N - 1);
  c = min(max(c, 0), N - 1);
  rowi[e] = r; coli[e] = c;
  atomicAdd(&deg[r], 1.0f);
  atomicAdd(&cnt[c], 1);
}

__global__ void k_dis(const float* __restrict__ deg, float* __restrict__ dis, int n) {
  int i = blockIdx.x * blockDim.x + threadIdx.x;
  if (i < n) {
    float d = deg[i];
    dis[i] = (d > 0.f) ? rsqrtf(d) : 0.f;
  }
}

// 1024-thread shuffle-based scan
__global__ __launch_bounds__(1024) void k_scan(const int* __restrict__ cnt,
                                               int* __restrict__ colPtr,
                                               int* __restrict__ cursor, int n) {
  __shared__ int ws[16];
  const int t = threadIdx.x;
  const int lane = t & 63;
  const int w = t >> 6;
  int carry = 0;
  for (int base = 0; base < n; base += 1024) {
    int i = base + t;
    int v = (i < n) ? cnt[i] : 0;
    int x = v;
#pragma unroll
    for (int off = 1; off < 64; off <<= 1) {
      int y = __shfl_up(x, off);
      if (lane >= off) x += y;
    }
    if (lane == 63) ws[w] = x;
    __syncthreads();
    if (w == 0) {
      int sv = (lane < 16) ? ws[lane] : 0;
#pragma unroll
      for (int off = 1; off < 16; off <<= 1) {
        int y = __shfl_up(sv, off);
        if (lane >= off) sv += y;
      }
      if (lane < 16) ws[lane] = sv;
    }
    __syncthreads();
    int woff = (w == 0) ? 0 : ws[w - 1];
    int incl = carry + woff + x;
    if (i < n) { colPtr[i + 1] = incl; cursor[i] = incl - v; }
    int tot = ws[15];
    __syncthreads();
    carry += tot;
  }
  if (t == 0) colPtr[0] = 0;
}

__global__ void k_place(const int* __restrict__ rowi, const int* __restrict__ coli,
                        const float* __restrict__ dis, int* __restrict__ cursor,
                        int* __restrict__ srcRow, float* __restrict__ srcW, int E) {
  int e = blockIdx.x * blockDim.x + threadIdx.x;
  if (e >= E) return;
  int r = rowi[e], c = coli[e];
  float wv = -dis[r] * dis[c];
  int pos = atomicAdd(&cursor[c], 1);
  srcRow[pos] = r;
  srcW[pos] = wv;
}

// v (bf16 or fp32) -> fp32 plane + hi/lo bf16 planes, 4 elems/thread
__global__ void k_convert(const void* __restrict__ v, const int* __restrict__ vflag,
                          float* __restrict__ xf, u16* __restrict__ xh,
                          u16* __restrict__ xl, int n4) {
  int i = blockIdx.x * blockDim.x + threadIdx.x;
  if (i >= n4) return;
  float val[4];
  if (*vflag) {
    float4 t = ((const float4*)v)[i];
    val[0] = t.x; val[1] = t.y; val[2] = t.z; val[3] = t.w;
  } else {
    ushort4 t = ((const ushort4*)v)[i];
    val[0] = bf2f(t.x); val[1] = bf2f(t.y); val[2] = bf2f(t.z); val[3] = bf2f(t.w);
  }
  float4 fo; ushort4 ho, lo;
  u16 h;
  h = f2bf(val[0]); ho.x = h; lo.x = f2bf(val[0] - bf2f(h)); fo.x = val[0];
  h = f2bf(val[1]); ho.y = h; lo.y = f2bf(val[1] - bf2f(h)); fo.y = val[1];
  h = f2bf(val[2]); ho.z = h; lo.z = f2bf(val[2] - bf2f(h)); fo.z = val[2];
  h = f2bf(val[3]); ho.w = h; lo.w = f2bf(val[3] - bf2f(h)); fo.w = val[3];
  ((float4*)xf)[i] = fo;
  ((ushort4*)xh)[i] = ho;
  ((ushort4*)xl)[i] = lo;
}

// ---------------- propagation F=128 (wave-per-node, paired edges, 4-deep) ----------------
// out[c,:] = alpha * sum_{e: col=c} w_e * z[row_e,:] + beta*base[c,:]
// Lanes 0-31 accumulate even edges, 32-63 odd edges; each half-wave reads a
// FULL 128-col row as float4 (16B/lane). 4 gathers in flight per iter
// (random-gather latency-bound -> outstanding-count is the lever).
__global__ __launch_bounds__(256) void k_prop128(
    const float* __restrict__ z, const float* __restrict__ base,
    float* __restrict__ outF, u16* __restrict__ outH, u16* __restrict__ outL,
    const int* __restrict__ colPtr, const int* __restrict__ srcRow,
    const float* __restrict__ srcW, int N, float alpha, float beta) {
  const int lane = threadIdx.x & 63;
  const int c = blockIdx.x * 4 + (threadIdx.x >> 6);
  if (c >= N) return;
  const int half = lane >> 5;          // edge parity this lane accumulates
  const int li = lane & 31;            // column group: cols 4*li..4*li+3
  const int s = colPtr[c], e = colPtr[c + 1];
  float4 accA = make_float4(0.f, 0.f, 0.f, 0.f);
  float4 accB = make_float4(0.f, 0.f, 0.f, 0.f);
  float4 accC = make_float4(0.f, 0.f, 0.f, 0.f);
  float4 accD = make_float4(0.f, 0.f, 0.f, 0.f);

  for (int j0 = s; j0 < e; j0 += 64) {
    const int take = min(64, e - j0);
    int rI = 0; float wI = 0.f;
    if (j0 + lane < e) { rI = srcRow[j0 + lane]; wI = srcW[j0 + lane]; }
    int jj = 0;
    for (; jj + 8 <= take; jj += 8) {          // 4 pairs (8 edges) per iter
      int   ra = __shfl(rI, jj + half);
      float wa = __shfl(wI, jj + half);
      int   rb = __shfl(rI, jj + 2 + half);
      float wb = __shfl(wI, jj + 2 + half);
      int   rc = __shfl(rI, jj + 4 + half);
      float wc = __shfl(wI, jj + 4 + half);
      int   rd = __shfl(rI, jj + 6 + half);
      float wd = __shfl(wI, jj + 6 + half);
      float4 za = *(const float4*)(z + (size_t)ra * 128 + li * 4);
      float4 zb = *(const float4*)(z + (size_t)rb * 128 + li * 4);
      float4 zc = *(const float4*)(z + (size_t)rc * 128 + li * 4);
      float4 zd = *(const float4*)(z + (size_t)rd * 128 + li * 4);
      accA.x = fmaf(wa, za.x, accA.x); accA.y = fmaf(wa, za.y, accA.y);
      accA.z = fmaf(wa, za.z, accA.z); accA.w = fmaf(wa, za.w, accA.w);
      accB.x = fmaf(wb, zb.x, accB.x); accB.y = fmaf(wb, zb.y, accB.y);
      accB.z = fmaf(wb, zb.z, accB.z); accB.w = fmaf(wb, zb.w, accB.w);
      accC.x = fmaf(wc, zc.x, accC.x); accC.y = fmaf(wc, zc.y, accC.y);
      accC.z = fmaf(wc, zc.z, accC.z); accC.w = fmaf(wc, zc.w, accC.w);
      accD.x = fmaf(wd, zd.x, accD.x); accD.y = fmaf(wd, zd.y, accD.y);
      accD.z = fmaf(wd, zd.z, accD.z); accD.w = fmaf(wd, zd.w, accD.w);
    }
    for (; jj < take; jj += 2) {               // tail: guarded lanes give w=0
      int   ra = __shfl(rI, jj + half);
      float wa = __shfl(wI, jj + half);
      float4 za = *(const float4*)(z + (size_t)ra * 128 + li * 4);
      accA.x = fmaf(wa, za.x, accA.x); accA.y = fmaf(wa, za.y, accA.y);
      accA.z = fmaf(wa, za.z, accA.z); accA.w = fmaf(wa, za.w, accA.w);
    }
  }

  float4 acc;
  acc.x = (accA.x + accB.x) + (accC.x + accD.x);
  acc.y = (accA.y + accB.y) + (accC.y + accD.y);
  acc.z = (accA.z + accB.z) + (accC.z + accD.z);
  acc.w = (accA.w + accB.w) + (accC.w + accD.w);
  acc.x += __shfl_xor(acc.x, 32);
  acc.y += __shfl_xor(acc.y, 32);
  acc.z += __shfl_xor(acc.z, 32);
  acc.w += __shfl_xor(acc.w, 32);

  if (lane < 32) {
    float vv[4] = {alpha * acc.x, alpha * acc.y, alpha * acc.z, alpha * acc.w};
    const size_t o = (size_t)c * 128 + li * 4;
    if (base != nullptr) {
      float4 b = *(const float4*)(base + o);
      vv[0] = fmaf(beta, b.x, vv[0]); vv[1] = fmaf(beta, b.y, vv[1]);
      vv[2] = fmaf(beta, b.z, vv[2]); vv[3] = fmaf(beta, b.w, vv[3]);
    }
    if (outF) *(float4*)(outF + o) = make_float4(vv[0], vv[1], vv[2], vv[3]);
    ushort4 ho, lo;
    u16 h;
    h = f2bf(vv[0]); ho.x = h; lo.x = f2bf(vv[0] - bf2f(h));
    h = f2bf(vv[1]); ho.y = h; lo.y = f2bf(vv[1] - bf2f(h));
    h = f2bf(vv[2]); ho.z = h; lo.z = f2bf(vv[2] - bf2f(h));
    h = f2bf(vv[3]); ho.w = h; lo.w = f2bf(vv[3] - bf2f(h));
    *(ushort4*)(outH + o) = ho;
    *(ushort4*)(outL + o) = lo;
  }
}

// ---------------- propagation F=256 (wave-per-node, full-row float4) ----------------
__global__ __launch_bounds__(256) void k_prop256(
    const float* __restrict__ z, const float* __restrict__ base,
    float* __restrict__ outF, u16* __restrict__ outH, u16* __restrict__ outL,
    const int* __restrict__ colPtr, const int* __restrict__ srcRow,
    const float* __restrict__ srcW, int N, float alpha, float beta) {
  const int lane = threadIdx.x & 63;
  const int c = blockIdx.x * 4 + (threadIdx.x >> 6);
  if (c >= N) return;
  const int s = colPtr[c], e = colPtr[c + 1];
  float4 accA = make_float4(0.f, 0.f, 0.f, 0.f);
  float4 accB = make_float4(0.f, 0.f, 0.f, 0.f);

  for (int j0 = s; j0 < e; j0 += 64) {
    const int take = min(64, e - j0);
    int rI = 0; float wI = 0.f;
    if (j0 + lane < e) { rI = srcRow[j0 + lane]; wI = srcW[j0 + lane]; }
    int jj = 0;
    for (; jj + 4 <= take; jj += 4) {
      int   r0 = __shfl(rI, jj),     r1 = __shfl(rI, jj + 1);
      int   r2 = __shfl(rI, jj + 2), r3 = __shfl(rI, jj + 3);
      float w0 = __shfl(wI, jj),     w1 = __shfl(wI, jj + 1);
      float w2 = __shfl(wI, jj + 2), w3 = __shfl(wI, jj + 3);
      float4 z0 = *(const float4*)(z + (size_t)r0 * 256 + lane * 4);
      float4 z1 = *(const float4*)(z + (size_t)r1 * 256 + lane * 4);
      float4 z2 = *(const float4*)(z + (size_t)r2 * 256 + lane * 4);
      float4 z3 = *(const float4*)(z + (size_t)r3 * 256 + lane * 4);
      accA.x = fmaf(w0, z0.x, accA.x); accA.y = fmaf(w0, z0.y, accA.y);
      accA.z = fmaf(w0, z0.z, accA.z); accA.w = fmaf(w0, z0.w, accA.w);
      accB.x = fmaf(w1, z1.x, accB.x); accB.y = fmaf(w1, z1.y, accB.y);
      accB.z = fmaf(w1, z1.z, accB.z); accB.w = fmaf(w1, z1.w, accB.w);
      accA.x = fmaf(w2, z2.x, accA.x); accA.y = fmaf(w2, z2.y, accA.y);
      accA.z = fmaf(w2, z2.z, accA.z); accA.w = fmaf(w2, z2.w, accA.w);
      accB.x = fmaf(w3, z3.x, accB.x); accB.y = fmaf(w3, z3.y, accB.y);
      accB.z = fmaf(w3, z3.z, accB.z); accB.w = fmaf(w3, z3.w, accB.w);
    }
    for (; jj < take; jj++) {
      int   r = __shfl(rI, jj);
      float w = __shfl(wI, jj);
      float4 zt = *(const float4*)(z + (size_t)r * 256 + lane * 4);
      accA.x = fmaf(w, zt.x, accA.x); accA.y = fmaf(w, zt.y, accA.y);
      accA.z = fmaf(w, zt.z, accA.z); accA.w = fmaf(w, zt.w, accA.w);
    }
  }

  float vv[4] = {alpha * (accA.x + accB.x), alpha * (accA.y + accB.y),
                 alpha * (accA.z + accB.z), alpha * (accA.w + accB.w)};
  const size_t o = (size_t)c * 256 + lane * 4;
  if (base != nullptr) {
    float4 b = *(const float4*)(base + o);
    vv[0] = fmaf(beta, b.x, vv[0]); vv[1] = fmaf(beta, b.y, vv[1]);
    vv[2] = fmaf(beta, b.z, vv[2]); vv[3] = fmaf(beta, b.w, vv[3]);
  }
  if (outF) *(float4*)(outF + o) = make_float4(vv[0], vv[1], vv[2], vv[3]);
  ushort4 ho, lo;
  u16 h;
  h = f2bf(vv[0]); ho.x = h; lo.x = f2bf(vv[0] - bf2f(h));
  h = f2bf(vv[1]); ho.y = h; lo.y = f2bf(vv[1] - bf2f(h));
  h = f2bf(vv[2]); ho.z = h; lo.z = f2bf(vv[2] - bf2f(h));
  h = f2bf(vv[3]); ho.w = h; lo.w = f2bf(vv[3] - bf2f(h));
  *(ushort4*)(outH + o) = ho;
  *(ushort4*)(outL + o) = lo;
}

// ---------------- MFMA GEMM (XCD swizzle + 2-phase double buffer) ----------------
// C[N,Fo] = maybe_relu( [A0|A1|A2] @ W + b ), A pre-split hi/lo bf16 planes,
// W pre-packed fragment-linear. Staging via global_load_lds width 16.
// Round-5 showed latency-bound (Mfma 19 / VALU 10 / HBM 12 all idle) with
// healthy L2 (FETCH 21.8 MB after XCD swizzle). Re-apply the 2-phase prefetch
// ON TOP of the swizzle: STAGE(next) issued before compute(cur), one
// vmcnt(0)+barrier per k-step. Round-3's blowout (FETCH 140 MB) was the
// UNSWIZZLED cross-XCD panel thrash; per-XCD footprint is now ~3 MB < 4 MB L2.
// Falsifiable: if FETCH blows past ~40 MB again, the theory is wrong -> revert.
// T5: setprio(1) around the MFMA cluster (2-phase gives wave role diversity).
// C/D mapping (verified): col = lane&31, row = (reg&3)+8*(reg>>2)+4*(lane>>5).
// LDS per buffer (1KB slots): 0-3 A-hi, 4-7 A-lo, 8-15 B-hi, 16-23 B-lo.
// headSplit: Fo=512 fused [mu|std] -> two N x 256 outputs at d_out, d_out+N*256.
__global__ __launch_bounds__(256, 3) void k_gemm_mfma(
    const u16* __restrict__ a0h, const u16* __restrict__ a0l,
    const u16* __restrict__ a1h, const u16* __restrict__ a1l,
    const u16* __restrict__ a2h, const u16* __restrict__ a2l,
    const u16* __restrict__ packHi, const u16* __restrict__ packLo,
    const void* __restrict__ bias, const void* __restrict__ bias2,
    const int* __restrict__ wflagp,
    int N, int Fi, int NQ, int Fo,
    float* __restrict__ outF, u16* __restrict__ outH, u16* __restrict__ outL,
    u16* __restrict__ outB16, float* __restrict__ outB32, int relu, int headSplit) {
  __shared__ bf16x8 sm[2 * 24 * 64];   // 48 KB, double-buffered

  const int wflag = *wflagp;
  const int tid  = threadIdx.x;
  const int lane = tid & 63;
  const int w    = tid >> 6;
  const int wm   = w >> 1;
  const int wn   = w & 1;

  // chunked-bijective XCD swizzle (m204): orig id -> contiguous chunk per XCD
  const int gx = gridDim.x;
  int wg = blockIdx.x + gx * blockIdx.y;
  {
    const int nwg = gx * gridDim.y;
    const int q = nwg >> 3, r = nwg & 7;
    const int xcd = wg & 7;
    const int idx = wg >> 3;
    wg = (xcd < r ? xcd * (q + 1) : r * (q + 1) + (xcd - r) * q) + idx;
  }
  const int nt = wg % gx;
  const int mt = wg / gx;
  const int n0 = nt << 7;
  const int m0 = mt << 6;
  const int KSQ  = Fi >> 5;                 // k-steps per source (pow2)
  const int qsh  = __builtin_ctz(KSQ);
  const int qmask = KSQ - 1;
  const int KS   = NQ << qsh;

  const int arow  = m0 + ((w >> 1) << 5) + (lane & 31);
  const int aeoff = ((w & 1) << 4) + ((lane >> 5) << 3);

  auto STAGE = [&](int buf, int ksn) {
    const int q  = ksn >> qsh;
    const int kk = (ksn & qmask) << 5;
    const u16* Ah = (q == 0) ? a0h : (q == 1 ? a1h : a2h);
    const u16* Al = (q == 0) ? a0l : (q == 1 ? a1l : a2l);
    const size_t aoff = (size_t)arow * Fi + kk + aeoff;
    bf16x8* sb = &sm[buf * 1536];
    gld16(Ah + aoff, sb + w * 64);
    gld16(Al + aoff, sb + (4 + w) * 64);
    const size_t boff = ((size_t)(nt * KS + ksn) * 8 + 2 * w) * 512 + lane * 8;
    gld16(packHi + boff,       sb + (8 + 2 * w) * 64);
    gld16(packHi + boff + 512, sb + (9 + 2 * w) * 64);
    if (wflag) {
      gld16(packLo + boff,       sb + (16 + 2 * w) * 64);
      gld16(packLo + boff + 512, sb + (17 + 2 * w) * 64);
    }
  };

  f32x16 acc0 = {}, acc1 = {};

  STAGE(0, 0);
  asm volatile("s_waitcnt vmcnt(0)" ::: "memory");
  __builtin_amdgcn_s_barrier();

  int cur = 0;
  for (int ks = 0; ks < KS; ks++) {
    const bool more = (ks + 1 < KS);
    if (more) STAGE(cur ^ 1, ks + 1);       // issue next-tile loads FIRST

    const bf16x8* sb = &sm[cur * 1536];
    const bf16x8 aH0 = sb[(wm * 2) * 64 + lane];
    const bf16x8 aH1 = sb[(wm * 2 + 1) * 64 + lane];
    const bf16x8 aL0 = sb[(4 + wm * 2) * 64 + lane];
    const bf16x8 aL1 = sb[(4 + wm * 2 + 1) * 64 + lane];
    const int bb = (8 + wn * 4) * 64 + lane;
    const bf16x8 b00 = sb[bb];
    const bf16x8 b01 = sb[bb + 64];
    const bf16x8 b10 = sb[bb + 128];
    const bf16x8 b11 = sb[bb + 192];

    __builtin_amdgcn_s_setprio(1);
    acc0 = __builtin_amdgcn_mfma_f32_32x32x16_bf16(aH0, b00, acc0, 0, 0, 0);
    acc0 = __builtin_amdgcn_mfma_f32_32x32x16_bf16(aL0, b00, acc0, 0, 0, 0);
    acc0 = __builtin_amdgcn_mfma_f32_32x32x16_bf16(aH1, b01, acc0, 0, 0, 0);
    acc0 = __builtin_amdgcn_mfma_f32_32x32x16_bf16(aL1, b01, acc0, 0, 0, 0);
    acc1 = __builtin_amdgcn_mfma_f32_32x32x16_bf16(aH0, b10, acc1, 0, 0, 0);
    acc1 = __builtin_amdgcn_mfma_f32_32x32x16_bf16(aL0, b10, acc1, 0, 0, 0);
    acc1 = __builtin_amdgcn_mfma_f32_32x32x16_bf16(aH1, b11, acc1, 0, 0, 0);
    acc1 = __builtin_amdgcn_mfma_f32_32x32x16_bf16(aL1, b11, acc1, 0, 0, 0);
    __builtin_amdgcn_s_setprio(0);
    if (wflag) {
      const int cb = (16 + wn * 4) * 64 + lane;
      const bf16x8 c00 = sb[cb];
      const bf16x8 c01 = sb[cb + 64];
      const bf16x8 c10 = sb[cb + 128];
      const bf16x8 c11 = sb[cb + 192];
      __builtin_amdgcn_s_setprio(1);
      acc0 = __builtin_amdgcn_mfma_f32_32x32x16_bf16(aH0, c00, acc0, 0, 0, 0);
      acc0 = __builtin_amdgcn_mfma_f32_32x32x16_bf16(aH1, c01, acc0, 0, 0, 0);
      acc1 = __builtin_amdgcn_mfma_f32_32x32x16_bf16(aH0, c10, acc1, 0, 0, 0);
      acc1 = __builtin_amdgcn_mfma_f32_32x32x16_bf16(aH1, c11, acc1, 0, 0, 0);
      __builtin_amdgcn_s_setprio(0);
    }

    if (more) {
      // next buffer's loads (this wave's own, issued above) complete; barrier
      // publishes all waves' LDS writes + gates buffer reuse
      asm volatile("s_waitcnt vmcnt(0)" ::: "memory");
      __builtin_amdgcn_s_barrier();
    }
    cur ^= 1;
  }

  // ---- epilogue ----
  auto epi = [&](const f32x16& acc, int nf) {
    const int ncol = n0 + (((wn << 1) + nf) << 5) + (lane & 31);
    int col = ncol;
    const void* bp = bias;
    size_t obase = 0;
    int FoOut = Fo;
    if (headSplit) {
      FoOut = 256;
      if (ncol >= 256) { col = ncol - 256; bp = bias2; obase = (size_t)N * 256; }
    }
    const float bv = wflag ? ((const float*)bp)[col]
                           : bf2f(((const u16*)bp)[col]);
#pragma unroll
    for (int r = 0; r < 16; r++) {
      const int m = m0 + (wm << 5) + (r & 3) + ((r >> 2) << 3) + ((lane >> 5) << 2);
      if (m < N) {
        float vv = acc[r] + bv;
        if (relu) vv = fmaxf(vv, 0.f);
        const size_t o = obase + (size_t)m * FoOut + col;
        if (outF) outF[o] = vv;
        if (outH) {
          u16 h = f2bf(vv);
          outH[o] = h;
          outL[o] = f2bf(vv - bf2f(h));
        }
        if (outB16) {
          if (wflag) outB32[o] = vv;
          else       outB16[o] = f2bf(vv);
        }
      }
    }
  };
  epi(acc0, 0);
  epi(acc1, 1);
}

// ---------------- host (kernel launches ONLY) ----------------

static size_t align256(size_t x) { return (x + 255) & ~(size_t)255; }

extern "C" void kernel_launch(void* const* d_in, const int* in_sizes, int n_in,
                              void* d_out, int out_size, void* d_ws, size_t ws_size,
                              hipStream_t stream) {
  const void* v    = d_in[0];
  const void* ei   = d_in[1];
  const void* W1   = d_in[2];
  const void* b1   = d_in[3];
  const void* W2   = d_in[4];
  const void* b2   = d_in[5];
  const void* W3   = d_in[6];
  const void* b3   = d_in[7];
  const void* Wmu  = d_in[8];
  const void* bmu  = d_in[9];
  const void* Wstd = d_in[10];
  const void* bstd = d_in[11];
  (void)n_in; (void)ws_size;

  const int N = in_sizes[0] / 128;   // 10000
  const int E = in_sizes[1] / 2;     // 160000
  const size_t NP = (size_t)N + 64;  // row padding: OOB A-tile rows stay mapped

  char* base = (char*)d_ws;
  size_t off = 0;
  auto carve = [&](size_t bytes) { void* p = base + off; off = align256(off + bytes); return p; };

  int*   eflag  = (int*)  carve(4);
  int*   vflag  = (int*)  carve(4);
  int*   rowi   = (int*)  carve((size_t)E * 4);
  int*   coli   = (int*)  carve((size_t)E * 4);
  float* deg    = (float*)carve((size_t)N * 4);
  float* dis    = (float*)carve((size_t)N * 4);
  int*   cnt    = (int*)  carve((size_t)N * 4);
  int*   colPtr = (int*)  carve((size_t)(N + 1) * 4);
  int*   cursor = (int*)  carve((size_t)N * 4);
  int*   srcRow = (int*)  carve((size_t)E * 4);
  float* srcW   = (float*)carve((size_t)E * 4);

  // weight packs (hi/lo); heads fused [mu|std] contiguously
  u16* pW1h = (u16*)carve((size_t)384 * 128 * 2);
  u16* pW1l = (u16*)carve((size_t)384 * 128 * 2);
  u16* pW2h = (u16*)carve((size_t)384 * 256 * 2);
  u16* pW2l = (u16*)carve((size_t)384 * 256 * 2);
  u16* pW3h = (u16*)carve((size_t)768 * 512 * 2);
  u16* pW3l = (u16*)carve((size_t)768 * 512 * 2);
  u16* pHh  = (u16*)carve((size_t)2 * 512 * 256 * 2);
  u16* pHl  = (u16*)carve((size_t)2 * 512 * 256 * 2);

  // activation planes
  float* Xf  = (float*)carve(NP * 256 * 4);
  u16*   Xh  = (u16*)  carve(NP * 256 * 2);
  u16*   Xl  = (u16*)  carve(NP * 256 * 2);
  float* Yf  = (float*)carve(NP * 128 * 4);
  u16*   Yh  = (u16*)  carve(NP * 512 * 2);
  u16*   Yl  = (u16*)  carve(NP * 512 * 2);
  float* t1f = (float*)carve(NP * 256 * 4);
  u16*   t1h = (u16*)  carve(NP * 256 * 2);
  u16*   t1l = (u16*)  carve(NP * 256 * 2);
  u16*   t2h = (u16*)  carve(NP * 256 * 2);
  u16*   t2l = (u16*)  carve(NP * 256 * 2);

  // 1) sentinel
  k_sentinel<<<(out_size + 255) / 256, 256, 0, stream>>>((u16*)d_out, out_size);

  // 2) dtype probes (merged)
  k_probe<<<2, 256, 0, stream>>>((const unsigned*)v, 1024, vflag,
                                 (const unsigned*)ei, 2048, eflag);

  // 3) weight pre-pack
  k_wpack<<< 24, 256, 0, stream>>>(W1,   vflag, 384, 128, pW1h, pW1l);
  k_wpack<<< 48, 256, 0, stream>>>(W2,   vflag, 384, 256, pW2h, pW2l);
  k_wpack<<<192, 256, 0, stream>>>(W3,   vflag, 768, 512, pW3h, pW3l);
  k_wpack<<< 64, 256, 0, stream>>>(Wmu,  vflag, 512, 256, pHh,            pHl);
  k_wpack<<< 64, 256, 0, stream>>>(Wstd, vflag, 512, 256, pHh + 131072,   pHl + 131072);

  // 4) graph preprocessing
  k_zero<<<(N + 255) / 256, 256, 0, stream>>>(deg, cnt, N);
  k_decode<<<(E + 255) / 256, 256, 0, stream>>>(ei, eflag, E, N, rowi, coli, deg, cnt);
  k_dis<<<(N + 255) / 256, 256, 0, stream>>>(deg, dis, N);
  k_scan<<<1, 1024, 0, stream>>>(cnt, colPtr, cursor, N);
  k_place<<<(E + 255) / 256, 256, 0, stream>>>(rowi, coli, dis, cursor, srcRow, srcW, E);
  k_convert<<<(N * 128 / 4 + 255) / 256, 256, 0, stream>>>(v, vflag, Xf, Xh, Xl, N * 128 / 4);

  const int gM = (N + 63) / 64;     // 157 m-tiles
  const int gP = (N + 3) / 4;       // wave-per-node prop blocks

  // layer 1: Fi=128 -> Fo=128, X -> Y
  k_prop128<<<gP, 256, 0, stream>>>(Xf, nullptr, t1f, t1h, t1l, colPtr, srcRow, srcW, N, 1.f, 0.f);
  k_prop128<<<gP, 256, 0, stream>>>(t1f, Xf, nullptr, t2h, t2l, colPtr, srcRow, srcW, N, 2.f, -1.f);
  k_gemm_mfma<<<dim3(1, gM), 256, 0, stream>>>(Xh, Xl, t1h, t1l, t2h, t2l, pW1h, pW1l,
                                               b1, b1, vflag, N, 128, 3, 128,
                                               Yf, Yh, Yl, nullptr, nullptr, 1, 0);

  // layer 2: Fi=128 -> Fo=256, Y -> X
  k_prop128<<<gP, 256, 0, stream>>>(Yf, nullptr, t1f, t1h, t1l, colPtr, srcRow, srcW, N, 1.f, 0.f);
  k_prop128<<<gP, 256, 0, stream>>>(t1f, Yf, nullptr, t2h, t2l, colPtr, srcRow, srcW, N, 2.f, -1.f);
  k_gemm_mfma<<<dim3(2, gM), 256, 0, stream>>>(Yh, Yl, t1h, t1l, t2h, t2l, pW2h, pW2l,
                                               b2, b2, vflag, N, 128, 3, 256,
                                               Xf, Xh, Xl, nullptr, nullptr, 1, 0);

  // layer 3: Fi=256 -> Fo=512, X -> Y (hi/lo only)
  k_prop256<<<gP, 256, 0, stream>>>(Xf, nullptr, t1f, t1h, t1l, colPtr, srcRow, srcW, N, 1.f, 0.f);
  k_prop256<<<gP, 256, 0, stream>>>(t1f, Xf, nullptr, t2h, t2l, colPtr, srcRow, srcW, N, 2.f, -1.f);
  k_gemm_mfma<<<dim3(4, gM), 256, 0, stream>>>(Xh, Xl, t1h, t1l, t2h, t2l, pW3h, pW3l,
                                               b3, b3, vflag, N, 256, 3, 512,
                                               nullptr, Yh, Yl, nullptr, nullptr, 1, 0);

  // fused heads: x3 (N x 512 hi/lo) @ [Wmu|Wstd] -> mu, std at d_out
  k_gemm_mfma<<<dim3(4, gM), 256, 0, stream>>>(Yh, Yl, nullptr, nullptr, nullptr, nullptr,
                                               pHh, pHl, bmu, bstd, vflag, N, 512, 1, 512,
                                               nullptr, nullptr, nullptr,
                                               (u16*)d_out, (float*)d_out, 0, 1);
}

// Round 7
// 352.135 us; speedup vs baseline: 1.4343x; 1.4343x over previous
//
#include <hip/hip_runtime.h>
#include <hip/hip_bf16.h>

// ---------------- types & helpers ----------------

typedef __attribute__((ext_vector_type(8)))  short bf16x8;   // 8 bf16 = 4 VGPR
typedef __attribute__((ext_vector_type(16))) float f32x16;   // MFMA 32x32 acc
typedef unsigned short u16;

__device__ __forceinline__ u16 f2bf(float x) {               // RNE fp32->bf16
  union { float f; unsigned u; } c; c.f = x;
  return (u16)((c.u + 0x7fffu + ((c.u >> 16) & 1u)) >> 16);
}
__device__ __forceinline__ float bf2f(u16 u) {               // exact bf16->fp32
  union { unsigned u; float f; } c; c.u = ((unsigned)u) << 16;
  return c.f;
}

// async global->LDS, 16B per lane; LDS dest = wave-uniform base + lane*16
__device__ __forceinline__ void gld16(const void* g, void* l) {
  __builtin_amdgcn_global_load_lds(
      (const __attribute__((address_space(1))) unsigned int*)g,
      (__attribute__((address_space(3))) unsigned int*)l, 16, 0, 0);
}

// ---------------- sentinel & merged dtype probe ----------------

__global__ void k_sentinel(u16* __restrict__ out, int n) {
  int i = blockIdx.x * blockDim.x + threadIdx.x;
  if (i < n) out[i] = 0x3F00;
}

// block 0: float dtype probe on v; block 1: edge-width probe on ei
__global__ void k_probe(const unsigned* __restrict__ v, int nv, int* __restrict__ vflag,
                        const unsigned* __restrict__ ei, int ne, int* __restrict__ eflag) {
  __shared__ unsigned red[256];
  if (blockIdx.x == 0) {
    int ok = 0;
    for (int i = threadIdx.x; i < nv; i += 256) {
      unsigned lo = v[i] & 0xffffu;
      unsigned ef = (lo >> 7) & 0xffu;
      if (ef >= 115u && ef <= 140u) ok++;
    }
    red[threadIdx.x] = (unsigned)ok;
    __syncthreads();
    for (int s = 128; s > 0; s >>= 1) {
      if (threadIdx.x < s) red[threadIdx.x] += red[threadIdx.x + s];
      __syncthreads();
    }
    if (threadIdx.x == 0) *vflag = ((int)red[0] < nv / 2) ? 1 : 0;
  } else {
    unsigned acc = 0;
    for (int i = threadIdx.x; i < ne; i += 256)
      if (i & 1) acc |= ei[i];
    red[threadIdx.x] = acc;
    __syncthreads();
    for (int s = 128; s > 0; s >>= 1) {
      if (threadIdx.x < s) red[threadIdx.x] |= red[threadIdx.x + s];
      __syncthreads();
    }
    if (threadIdx.x == 0) *eflag = (red[0] == 0u) ? 1 : 0;
  }
}

// ---------------- weight pre-pack (64-wide n-tiles) ----------------
// Pack W[K][Fo] into fragment-linear slots: slot s = (nt*KS + ks)*4 + fb,
// fb = (nblock<<1)|kchunk, lane l holds 8 bf16:
//   W[ks*32 + (fb&1)*16 + (l>>5)*8 + j][nt*64 + (fb>>1)*32 + (l&31)].
// Slot = 64 lanes x 16B contiguous -> GEMM B-staging is one coalesced gld16.
__global__ void k_wpack(const void* __restrict__ W, const int* __restrict__ wflagp,
                        int K, int Fo, u16* __restrict__ dstHi, u16* __restrict__ dstLo) {
  const int t = blockIdx.x * 256 + threadIdx.x;
  const int KS = K >> 5;
  const int total = (Fo >> 6) * KS * 4;
  const int s = t >> 6;
  if (s >= total) return;
  const int lane = t & 63;
  const int fb = s & 3;
  const int sk = s >> 2;
  const int ks = sk % KS;
  const int nt = sk / KS;
  const int col = (nt << 6) + ((fb >> 1) << 5) + (lane & 31);
  const int row = (ks << 5) + ((fb & 1) << 4) + ((lane >> 5) << 3);
  const int wflag = *wflagp;
  bf16x8 hi;
  if (wflag) {
    const float* Wf = (const float*)W;
    bf16x8 lo;
#pragma unroll
    for (int j = 0; j < 8; j++) {
      float wv = Wf[(size_t)(row + j) * Fo + col];
      u16 h = f2bf(wv);
      hi[j] = (short)h;
      lo[j] = (short)f2bf(wv - bf2f(h));
    }
    *(bf16x8*)(dstLo + (size_t)s * 512 + lane * 8) = lo;
  } else {
    const u16* Wb = (const u16*)W;
#pragma unroll
    for (int j = 0; j < 8; j++)
      hi[j] = (short)Wb[(size_t)(row + j) * Fo + col];
  }
  *(bf16x8*)(dstHi + (size_t)s * 512 + lane * 8) = hi;
}

// ---------------- preprocessing ----------------

__global__ void k_zero(float* __restrict__ deg, int* __restrict__ cnt, int n) {
  int i = blockIdx.x * blockDim.x + threadIdx.x;
  if (i < n) { deg[i] = 0.0f; cnt[i] = 0; }
}

__global__ void k_decode(const void* __restrict__ ei, const int* __restrict__ eflag,
                         int E, int N, int* __restrict__ rowi, int* __restrict__ coli,
                         float* __restrict__ deg, int* __restrict__ cnt) {
  int e = blockIdx.x * blockDim.x + threadIdx.x;
  if (e >= E) return;
  int f = *eflag;
  int r, c;
  if (f) {
    const long long* q = (const long long*)ei;
    r = (int)q[e]; c = (int)q[e + E];
  } else {
    const int* q = (const int*)ei;
    r = q[e]; c = q[e + E];
  }
  r = min(max(r, 0), N - 1);
  c = min(max(c, 0), N - 1);
  rowi[e] = r; coli[e] = c;
  atomicAdd(&deg[r], 1.0f);
  atomicAdd(&cnt[c], 1);
}

__global__ void k_dis(const float* __restrict__ deg, float* __restrict__ dis, int n) {
  int i = blockIdx.x * blockDim.x + threadIdx.x;
  if (i < n) {
    float d = deg[i];
    dis[i] = (d > 0.f) ? rsqrtf(d) : 0.f;
  }
}

// 1024-thread shuffle-based scan
__global__ __launch_bounds__(1024) void k_scan(const int* __restrict__ cnt,
                                               int* __restrict__ colPtr,
                                               int* __restrict__ cursor, int n) {
  __shared__ int ws[16];
  const int t = threadIdx.x;
  const int lane = t & 63;
  const int w = t >> 6;
  int carry = 0;
  for (int base = 0; base < n; base += 1024) {
    int i = base + t;
    int v = (i < n) ? cnt[i] : 0;
    int x = v;
#pragma unroll
    for (int off = 1; off < 64; off <<= 1) {
      int y = __shfl_up(x, off);
      if (lane >= off) x += y;
    }
    if (lane == 63) ws[w] = x;
    __syncthreads();
    if (w == 0) {
      int sv = (lane < 16) ? ws[lane] : 0;
#pragma unroll
      for (int off = 1; off < 16; off <<= 1) {
        int y = __shfl_up(sv, off);
        if (lane >= off) sv += y;
      }
      if (lane < 16) ws[lane] = sv;
    }
    __syncthreads();
    int woff = (w == 0) ? 0 : ws[w - 1];
    int incl = carry + woff + x;
    if (i < n) { colPtr[i + 1] = incl; cursor[i] = incl - v; }
    int tot = ws[15];
    __syncthreads();
    carry += tot;
  }
  if (t == 0) colPtr[0] = 0;
}

__global__ void k_place(const int* __restrict__ rowi, const int* __restrict__ coli,
                        const float* __restrict__ dis, int* __restrict__ cursor,
                        int* __restrict__ srcRow, float* __restrict__ srcW, int E) {
  int e = blockIdx.x * blockDim.x + threadIdx.x;
  if (e >= E) return;
  int r = rowi[e], c = coli[e];
  float wv = -dis[r] * dis[c];
  int pos = atomicAdd(&cursor[c], 1);
  srcRow[pos] = r;
  srcW[pos] = wv;
}

// v (bf16 or fp32) -> fp32 plane + hi/lo bf16 planes, 4 elems/thread
__global__ void k_convert(const void* __restrict__ v, const int* __restrict__ vflag,
                          float* __restrict__ xf, u16* __restrict__ xh,
                          u16* __restrict__ xl, int n4) {
  int i = blockIdx.x * blockDim.x + threadIdx.x;
  if (i >= n4) return;
  float val[4];
  if (*vflag) {
    float4 t = ((const float4*)v)[i];
    val[0] = t.x; val[1] = t.y; val[2] = t.z; val[3] = t.w;
  } else {
    ushort4 t = ((const ushort4*)v)[i];
    val[0] = bf2f(t.x); val[1] = bf2f(t.y); val[2] = bf2f(t.z); val[3] = bf2f(t.w);
  }
  float4 fo; ushort4 ho, lo;
  u16 h;
  h = f2bf(val[0]); ho.x = h; lo.x = f2bf(val[0] - bf2f(h)); fo.x = val[0];
  h = f2bf(val[1]); ho.y = h; lo.y = f2bf(val[1] - bf2f(h)); fo.y = val[1];
  h = f2bf(val[2]); ho.z = h; lo.z = f2bf(val[2] - bf2f(h)); fo.z = val[2];
  h = f2bf(val[3]); ho.w = h; lo.w = f2bf(val[3] - bf2f(h)); fo.w = val[3];
  ((float4*)xf)[i] = fo;
  ((ushort4*)xh)[i] = ho;
  ((ushort4*)xl)[i] = lo;
}

// ---------------- propagation F=128 (wave-per-node, paired edges, 4-deep) ----------------
__global__ __launch_bounds__(256) void k_prop128(
    const float* __restrict__ z, const float* __restrict__ base,
    float* __restrict__ outF, u16* __restrict__ outH, u16* __restrict__ outL,
    const int* __restrict__ colPtr, const int* __restrict__ srcRow,
    const float* __restrict__ srcW, int N, float alpha, float beta) {
  const int lane = threadIdx.x & 63;
  const int c = blockIdx.x * 4 + (threadIdx.x >> 6);
  if (c >= N) return;
  const int half = lane >> 5;          // edge parity this lane accumulates
  const int li = lane & 31;            // column group: cols 4*li..4*li+3
  const int s = colPtr[c], e = colPtr[c + 1];
  float4 accA = make_float4(0.f, 0.f, 0.f, 0.f);
  float4 accB = make_float4(0.f, 0.f, 0.f, 0.f);
  float4 accC = make_float4(0.f, 0.f, 0.f, 0.f);
  float4 accD = make_float4(0.f, 0.f, 0.f, 0.f);

  for (int j0 = s; j0 < e; j0 += 64) {
    const int take = min(64, e - j0);
    int rI = 0; float wI = 0.f;
    if (j0 + lane < e) { rI = srcRow[j0 + lane]; wI = srcW[j0 + lane]; }
    int jj = 0;
    for (; jj + 8 <= take; jj += 8) {          // 4 pairs (8 edges) per iter
      int   ra = __shfl(rI, jj + half);
      float wa = __shfl(wI, jj + half);
      int   rb = __shfl(rI, jj + 2 + half);
      float wb = __shfl(wI, jj + 2 + half);
      int   rc = __shfl(rI, jj + 4 + half);
      float wc = __shfl(wI, jj + 4 + half);
      int   rd = __shfl(rI, jj + 6 + half);
      float wd = __shfl(wI, jj + 6 + half);
      float4 za = *(const float4*)(z + (size_t)ra * 128 + li * 4);
      float4 zb = *(const float4*)(z + (size_t)rb * 128 + li * 4);
      float4 zc = *(const float4*)(z + (size_t)rc * 128 + li * 4);
      float4 zd = *(const float4*)(z + (size_t)rd * 128 + li * 4);
      accA.x = fmaf(wa, za.x, accA.x); accA.y = fmaf(wa, za.y, accA.y);
      accA.z = fmaf(wa, za.z, accA.z); accA.w = fmaf(wa, za.w, accA.w);
      accB.x = fmaf(wb, zb.x, accB.x); accB.y = fmaf(wb, zb.y, accB.y);
      accB.z = fmaf(wb, zb.z, accB.z); accB.w = fmaf(wb, zb.w, accB.w);
      accC.x = fmaf(wc, zc.x, accC.x); accC.y = fmaf(wc, zc.y, accC.y);
      accC.z = fmaf(wc, zc.z, accC.z); accC.w = fmaf(wc, zc.w, accC.w);
      accD.x = fmaf(wd, zd.x, accD.x); accD.y = fmaf(wd, zd.y, accD.y);
      accD.z = fmaf(wd, zd.z, accD.z); accD.w = fmaf(wd, zd.w, accD.w);
    }
    for (; jj < take; jj += 2) {               // tail: guarded lanes give w=0
      int   ra = __shfl(rI, jj + half);
      float wa = __shfl(wI, jj + half);
      float4 za = *(const float4*)(z + (size_t)ra * 128 + li * 4);
      accA.x = fmaf(wa, za.x, accA.x); accA.y = fmaf(wa, za.y, accA.y);
      accA.z = fmaf(wa, za.z, accA.z); accA.w = fmaf(wa, za.w, accA.w);
    }
  }

  float4 acc;
  acc.x = (accA.x + accB.x) + (accC.x + accD.x);
  acc.y = (accA.y + accB.y) + (accC.y + accD.y);
  acc.z = (accA.z + accB.z) + (accC.z + accD.z);
  acc.w = (accA.w + accB.w) + (accC.w + accD.w);
  acc.x += __shfl_xor(acc.x, 32);
  acc.y += __shfl_xor(acc.y, 32);
  acc.z += __shfl_xor(acc.z, 32);
  acc.w += __shfl_xor(acc.w, 32);

  if (lane < 32) {
    float vv[4] = {alpha * acc.x, alpha * acc.y, alpha * acc.z, alpha * acc.w};
    const size_t o = (size_t)c * 128 + li * 4;
    if (base != nullptr) {
      float4 b = *(const float4*)(base + o);
      vv[0] = fmaf(beta, b.x, vv[0]); vv[1] = fmaf(beta, b.y, vv[1]);
      vv[2] = fmaf(beta, b.z, vv[2]); vv[3] = fmaf(beta, b.w, vv[3]);
    }
    if (outF) *(float4*)(outF + o) = make_float4(vv[0], vv[1], vv[2], vv[3]);
    ushort4 ho, lo;
    u16 h;
    h = f2bf(vv[0]); ho.x = h; lo.x = f2bf(vv[0] - bf2f(h));
    h = f2bf(vv[1]); ho.y = h; lo.y = f2bf(vv[1] - bf2f(h));
    h = f2bf(vv[2]); ho.z = h; lo.z = f2bf(vv[2] - bf2f(h));
    h = f2bf(vv[3]); ho.w = h; lo.w = f2bf(vv[3] - bf2f(h));
    *(ushort4*)(outH + o) = ho;
    *(ushort4*)(outL + o) = lo;
  }
}

// ---------------- propagation F=256 (wave-per-node, full-row float4) ----------------
__global__ __launch_bounds__(256) void k_prop256(
    const float* __restrict__ z, const float* __restrict__ base,
    float* __restrict__ outF, u16* __restrict__ outH, u16* __restrict__ outL,
    const int* __restrict__ colPtr, const int* __restrict__ srcRow,
    const float* __restrict__ srcW, int N, float alpha, float beta) {
  const int lane = threadIdx.x & 63;
  const int c = blockIdx.x * 4 + (threadIdx.x >> 6);
  if (c >= N) return;
  const int s = colPtr[c], e = colPtr[c + 1];
  float4 accA = make_float4(0.f, 0.f, 0.f, 0.f);
  float4 accB = make_float4(0.f, 0.f, 0.f, 0.f);

  for (int j0 = s; j0 < e; j0 += 64) {
    const int take = min(64, e - j0);
    int rI = 0; float wI = 0.f;
    if (j0 + lane < e) { rI = srcRow[j0 + lane]; wI = srcW[j0 + lane]; }
    int jj = 0;
    for (; jj + 4 <= take; jj += 4) {
      int   r0 = __shfl(rI, jj),     r1 = __shfl(rI, jj + 1);
      int   r2 = __shfl(rI, jj + 2), r3 = __shfl(rI, jj + 3);
      float w0 = __shfl(wI, jj),     w1 = __shfl(wI, jj + 1);
      float w2 = __shfl(wI, jj + 2), w3 = __shfl(wI, jj + 3);
      float4 z0 = *(const float4*)(z + (size_t)r0 * 256 + lane * 4);
      float4 z1 = *(const float4*)(z + (size_t)r1 * 256 + lane * 4);
      float4 z2 = *(const float4*)(z + (size_t)r2 * 256 + lane * 4);
      float4 z3 = *(const float4*)(z + (size_t)r3 * 256 + lane * 4);
      accA.x = fmaf(w0, z0.x, accA.x); accA.y = fmaf(w0, z0.y, accA.y);
      accA.z = fmaf(w0, z0.z, accA.z); accA.w = fmaf(w0, z0.w, accA.w);
      accB.x = fmaf(w1, z1.x, accB.x); accB.y = fmaf(w1, z1.y, accB.y);
      accB.z = fmaf(w1, z1.z, accB.z); accB.w = fmaf(w1, z1.w, accB.w);
      accA.x = fmaf(w2, z2.x, accA.x); accA.y = fmaf(w2, z2.y, accA.y);
      accA.z = fmaf(w2, z2.z, accA.z); accA.w = fmaf(w2, z2.w, accA.w);
      accB.x = fmaf(w3, z3.x, accB.x); accB.y = fmaf(w3, z3.y, accB.y);
      accB.z = fmaf(w3, z3.z, accB.z); accB.w = fmaf(w3, z3.w, accB.w);
    }
    for (; jj < take; jj++) {
      int   r = __shfl(rI, jj);
      float w = __shfl(wI, jj);
      float4 zt = *(const float4*)(z + (size_t)r * 256 + lane * 4);
      accA.x = fmaf(w, zt.x, accA.x); accA.y = fmaf(w, zt.y, accA.y);
      accA.z = fmaf(w, zt.z, accA.z); accA.w = fmaf(w, zt.w, accA.w);
    }
  }

  float vv[4] = {alpha * (accA.x + accB.x), alpha * (accA.y + accB.y),
                 alpha * (accA.z + accB.z), alpha * (accA.w + accB.w)};
  const size_t o = (size_t)c * 256 + lane * 4;
  if (base != nullptr) {
    float4 b = *(const float4*)(base + o);
    vv[0] = fmaf(beta, b.x, vv[0]); vv[1] = fmaf(beta, b.y, vv[1]);
    vv[2] = fmaf(beta, b.z, vv[2]); vv[3] = fmaf(beta, b.w, vv[3]);
  }
  if (outF) *(float4*)(outF + o) = make_float4(vv[0], vv[1], vv[2], vv[3]);
  ushort4 ho, lo;
  u16 h;
  h = f2bf(vv[0]); ho.x = h; lo.x = f2bf(vv[0] - bf2f(h));
  h = f2bf(vv[1]); ho.y = h; lo.y = f2bf(vv[1] - bf2f(h));
  h = f2bf(vv[2]); ho.z = h; lo.z = f2bf(vv[2] - bf2f(h));
  h = f2bf(vv[3]); ho.w = h; lo.w = f2bf(vv[3] - bf2f(h));
  *(ushort4*)(outH + o) = ho;
  *(ushort4*)(outL + o) = lo;
}

// ---------------- MFMA GEMM (64x64 tile, single-buffer, XCD swizzle) ----------------
// C[N,Fo] = maybe_relu( [A0|A1|A2] @ W + b ), A pre-split hi/lo bf16 planes,
// W pre-packed fragment-linear (64-wide). Staging via global_load_lds w=16.
// LESSONS: (r3/r6, A/B/A/B-confirmed) double-buffered 2-phase prefetch is
// structurally ~2.4x SLOWER here regardless of swizzle -> single buffer,
// two barriers per k-step, period. (r5) the kernel is latency-bound and
// GRID-STARVED (Occupancy ~19%, 0.6-2.5 blocks/CU) -> this round shrinks
// the tile 64x128 -> 64x64 (1 frag/wave, 16KB LDS, 6 blocks/CU) to double
// the block count and hide latency with TLP instead of pipelining.
// C/D mapping (verified): col = lane&31, row = (reg&3)+8*(reg>>2)+4*(lane>>5).
// LDS slots (1KB): 0-3 A-hi, 4-7 A-lo, 8-11 B-hi, 12-15 B-lo.
// headSplit: Fo=512 fused [mu|std] -> two N x 256 outputs at d_out, d_out+N*256.
__global__ __launch_bounds__(256, 6) void k_gemm_mfma(
    const u16* __restrict__ a0h, const u16* __restrict__ a0l,
    const u16* __restrict__ a1h, const u16* __restrict__ a1l,
    const u16* __restrict__ a2h, const u16* __restrict__ a2l,
    const u16* __restrict__ packHi, const u16* __restrict__ packLo,
    const void* __restrict__ bias, const void* __restrict__ bias2,
    const int* __restrict__ wflagp,
    int N, int Fi, int NQ, int Fo,
    float* __restrict__ outF, u16* __restrict__ outH, u16* __restrict__ outL,
    u16* __restrict__ outB16, float* __restrict__ outB32, int relu, int headSplit) {
  __shared__ bf16x8 sm[16 * 64];   // 16 KB single buffer

  const int wflag = *wflagp;
  const int tid  = threadIdx.x;
  const int lane = tid & 63;
  const int w    = tid >> 6;
  const int wm   = w >> 1;
  const int wn   = w & 1;

  // chunked-bijective XCD swizzle (m204): orig id -> contiguous chunk per XCD
  const int gx = gridDim.x;
  int wg = blockIdx.x + gx * blockIdx.y;
  {
    const int nwg = gx * gridDim.y;
    const int q = nwg >> 3, r = nwg & 7;
    const int xcd = wg & 7;
    const int idx = wg >> 3;
    wg = (xcd < r ? xcd * (q + 1) : r * (q + 1) + (xcd - r) * q) + idx;
  }
  const int nt = wg % gx;
  const int mt = wg / gx;
  const int n0 = nt << 6;
  const int m0 = mt << 6;
  const int KS = (NQ * Fi) >> 5;

  const int arow  = m0 + ((w >> 1) << 5) + (lane & 31);
  const int aeoff = ((w & 1) << 4) + ((lane >> 5) << 3);

  f32x16 acc = {};

  int q = 0, kk = 0;
  for (int ks = 0; ks < KS; ks++) {
    const u16* Ah = (q == 0) ? a0h : (q == 1 ? a1h : a2h);
    const u16* Al = (q == 0) ? a0l : (q == 1 ? a1l : a2l);
    const size_t aoff = (size_t)arow * Fi + kk + aeoff;
    gld16(Ah + aoff, &sm[w * 64]);
    gld16(Al + aoff, &sm[(4 + w) * 64]);
    const size_t boff = ((size_t)(nt * KS + ks) * 4 + w) * 512 + lane * 8;
    gld16(packHi + boff, &sm[(8 + w) * 64]);
    if (wflag) gld16(packLo + boff, &sm[(12 + w) * 64]);
    __syncthreads();   // drains vmcnt (global_load_lds) before frag reads

    const bf16x8 aH0 = sm[(wm * 2) * 64 + lane];
    const bf16x8 aH1 = sm[(wm * 2 + 1) * 64 + lane];
    const bf16x8 aL0 = sm[(4 + wm * 2) * 64 + lane];
    const bf16x8 aL1 = sm[(4 + wm * 2 + 1) * 64 + lane];
    const bf16x8 b0  = sm[(8 + wn * 2) * 64 + lane];
    const bf16x8 b1  = sm[(8 + wn * 2 + 1) * 64 + lane];

    acc = __builtin_amdgcn_mfma_f32_32x32x16_bf16(aH0, b0, acc, 0, 0, 0);
    acc = __builtin_amdgcn_mfma_f32_32x32x16_bf16(aL0, b0, acc, 0, 0, 0);
    acc = __builtin_amdgcn_mfma_f32_32x32x16_bf16(aH1, b1, acc, 0, 0, 0);
    acc = __builtin_amdgcn_mfma_f32_32x32x16_bf16(aL1, b1, acc, 0, 0, 0);
    if (wflag) {
      const bf16x8 c0 = sm[(12 + wn * 2) * 64 + lane];
      const bf16x8 c1 = sm[(12 + wn * 2 + 1) * 64 + lane];
      acc = __builtin_amdgcn_mfma_f32_32x32x16_bf16(aH0, c0, acc, 0, 0, 0);
      acc = __builtin_amdgcn_mfma_f32_32x32x16_bf16(aH1, c1, acc, 0, 0, 0);
    }
    __syncthreads();

    kk += 32;
    if (kk == Fi) { kk = 0; q++; }
  }

  // ---- epilogue (single 32x32 frag per wave) ----
  {
    const int ncol = n0 + (wn << 5) + (lane & 31);
    int col = ncol;
    const void* bp = bias;
    size_t obase = 0;
    int FoOut = Fo;
    if (headSplit) {
      FoOut = 256;
      if (ncol >= 256) { col = ncol - 256; bp = bias2; obase = (size_t)N * 256; }
    }
    const float bv = wflag ? ((const float*)bp)[col]
                           : bf2f(((const u16*)bp)[col]);
#pragma unroll
    for (int r = 0; r < 16; r++) {
      const int m = m0 + (wm << 5) + (r & 3) + ((r >> 2) << 3) + ((lane >> 5) << 2);
      if (m < N) {
        float vv = acc[r] + bv;
        if (relu) vv = fmaxf(vv, 0.f);
        const size_t o = obase + (size_t)m * FoOut + col;
        if (outF) outF[o] = vv;
        if (outH) {
          u16 h = f2bf(vv);
          outH[o] = h;
          outL[o] = f2bf(vv - bf2f(h));
        }
        if (outB16) {
          if (wflag) outB32[o] = vv;
          else       outB16[o] = f2bf(vv);
        }
      }
    }
  }
}

// ---------------- host (kernel launches ONLY) ----------------

static size_t align256(size_t x) { return (x + 255) & ~(size_t)255; }

extern "C" void kernel_launch(void* const* d_in, const int* in_sizes, int n_in,
                              void* d_out, int out_size, void* d_ws, size_t ws_size,
                              hipStream_t stream) {
  const void* v    = d_in[0];
  const void* ei   = d_in[1];
  const void* W1   = d_in[2];
  const void* b1   = d_in[3];
  const void* W2   = d_in[4];
  const void* b2   = d_in[5];
  const void* W3   = d_in[6];
  const void* b3   = d_in[7];
  const void* Wmu  = d_in[8];
  const void* bmu  = d_in[9];
  const void* Wstd = d_in[10];
  const void* bstd = d_in[11];
  (void)n_in; (void)ws_size;

  const int N = in_sizes[0] / 128;   // 10000
  const int E = in_sizes[1] / 2;     // 160000
  const size_t NP = (size_t)N + 64;  // row padding: OOB A-tile rows stay mapped

  char* base = (char*)d_ws;
  size_t off = 0;
  auto carve = [&](size_t bytes) { void* p = base + off; off = align256(off + bytes); return p; };

  int*   eflag  = (int*)  carve(4);
  int*   vflag  = (int*)  carve(4);
  int*   rowi   = (int*)  carve((size_t)E * 4);
  int*   coli   = (int*)  carve((size_t)E * 4);
  float* deg    = (float*)carve((size_t)N * 4);
  float* dis    = (float*)carve((size_t)N * 4);
  int*   cnt    = (int*)  carve((size_t)N * 4);
  int*   colPtr = (int*)  carve((size_t)(N + 1) * 4);
  int*   cursor = (int*)  carve((size_t)N * 4);
  int*   srcRow = (int*)  carve((size_t)E * 4);
  float* srcW   = (float*)carve((size_t)E * 4);

  // weight packs (hi/lo); heads fused [mu|std] contiguously
  u16* pW1h = (u16*)carve((size_t)384 * 128 * 2);
  u16* pW1l = (u16*)carve((size_t)384 * 128 * 2);
  u16* pW2h = (u16*)carve((size_t)384 * 256 * 2);
  u16* pW2l = (u16*)carve((size_t)384 * 256 * 2);
  u16* pW3h = (u16*)carve((size_t)768 * 512 * 2);
  u16* pW3l = (u16*)carve((size_t)768 * 512 * 2);
  u16* pHh  = (u16*)carve((size_t)2 * 512 * 256 * 2);
  u16* pHl  = (u16*)carve((size_t)2 * 512 * 256 * 2);

  // activation planes
  float* Xf  = (float*)carve(NP * 256 * 4);
  u16*   Xh  = (u16*)  carve(NP * 256 * 2);
  u16*   Xl  = (u16*)  carve(NP * 256 * 2);
  float* Yf  = (float*)carve(NP * 128 * 4);
  u16*   Yh  = (u16*)  carve(NP * 512 * 2);
  u16*   Yl  = (u16*)  carve(NP * 512 * 2);
  float* t1f = (float*)carve(NP * 256 * 4);
  u16*   t1h = (u16*)  carve(NP * 256 * 2);
  u16*   t1l = (u16*)  carve(NP * 256 * 2);
  u16*   t2h = (u16*)  carve(NP * 256 * 2);
  u16*   t2l = (u16*)  carve(NP * 256 * 2);

  // 1) sentinel
  k_sentinel<<<(out_size + 255) / 256, 256, 0, stream>>>((u16*)d_out, out_size);

  // 2) dtype probes (merged)
  k_probe<<<2, 256, 0, stream>>>((const unsigned*)v, 1024, vflag,
                                 (const unsigned*)ei, 2048, eflag);

  // 3) weight pre-pack (64-wide tiles; same slot totals as before)
  k_wpack<<< 24, 256, 0, stream>>>(W1,   vflag, 384, 128, pW1h, pW1l);
  k_wpack<<< 48, 256, 0, stream>>>(W2,   vflag, 384, 256, pW2h, pW2l);
  k_wpack<<<192, 256, 0, stream>>>(W3,   vflag, 768, 512, pW3h, pW3l);
  k_wpack<<< 64, 256, 0, stream>>>(Wmu,  vflag, 512, 256, pHh,            pHl);
  k_wpack<<< 64, 256, 0, stream>>>(Wstd, vflag, 512, 256, pHh + 131072,   pHl + 131072);

  // 4) graph preprocessing
  k_zero<<<(N + 255) / 256, 256, 0, stream>>>(deg, cnt, N);
  k_decode<<<(E + 255) / 256, 256, 0, stream>>>(ei, eflag, E, N, rowi, coli, deg, cnt);
  k_dis<<<(N + 255) / 256, 256, 0, stream>>>(deg, dis, N);
  k_scan<<<1, 1024, 0, stream>>>(cnt, colPtr, cursor, N);
  k_place<<<(E + 255) / 256, 256, 0, stream>>>(rowi, coli, dis, cursor, srcRow, srcW, E);
  k_convert<<<(N * 128 / 4 + 255) / 256, 256, 0, stream>>>(v, vflag, Xf, Xh, Xl, N * 128 / 4);

  const int gM = (N + 63) / 64;     // 157 m-tiles
  const int gP = (N + 3) / 4;       // wave-per-node prop blocks

  // layer 1: Fi=128 -> Fo=128, X -> Y   (grid 2x157 = 314 blocks)
  k_prop128<<<gP, 256, 0, stream>>>(Xf, nullptr, t1f, t1h, t1l, colPtr, srcRow, srcW, N, 1.f, 0.f);
  k_prop128<<<gP, 256, 0, stream>>>(t1f, Xf, nullptr, t2h, t2l, colPtr, srcRow, srcW, N, 2.f, -1.f);
  k_gemm_mfma<<<dim3(2, gM), 256, 0, stream>>>(Xh, Xl, t1h, t1l, t2h, t2l, pW1h, pW1l,
                                               b1, b1, vflag, N, 128, 3, 128,
                                               Yf, Yh, Yl, nullptr, nullptr, 1, 0);

  // layer 2: Fi=128 -> Fo=256, Y -> X   (grid 4x157 = 628 blocks)
  k_prop128<<<gP, 256, 0, stream>>>(Yf, nullptr, t1f, t1h, t1l, colPtr, srcRow, srcW, N, 1.f, 0.f);
  k_prop128<<<gP, 256, 0, stream>>>(t1f, Yf, nullptr, t2h, t2l, colPtr, srcRow, srcW, N, 2.f, -1.f);
  k_gemm_mfma<<<dim3(4, gM), 256, 0, stream>>>(Yh, Yl, t1h, t1l, t2h, t2l, pW2h, pW2l,
                                               b2, b2, vflag, N, 128, 3, 256,
                                               Xf, Xh, Xl, nullptr, nullptr, 1, 0);

  // layer 3: Fi=256 -> Fo=512, X -> Y   (grid 8x157 = 1256 blocks)
  k_prop256<<<gP, 256, 0, stream>>>(Xf, nullptr, t1f, t1h, t1l, colPtr, srcRow, srcW, N, 1.f, 0.f);
  k_prop256<<<gP, 256, 0, stream>>>(t1f, Xf, nullptr, t2h, t2l, colPtr, srcRow, srcW, N, 2.f, -1.f);
  k_gemm_mfma<<<dim3(8, gM), 256, 0, stream>>>(Xh, Xl, t1h, t1l, t2h, t2l, pW3h, pW3l,
                                               b3, b3, vflag, N, 256, 3, 512,
                                               nullptr, Yh, Yl, nullptr, nullptr, 1, 0);

  // fused heads: x3 (N x 512 hi/lo) @ [Wmu|Wstd] -> mu, std at d_out (8x157)
  k_gemm_mfma<<<dim3(8, gM), 256, 0, stream>>>(Yh, Yl, nullptr, nullptr, nullptr, nullptr,
                                               pHh, pHl, bmu, bstd, vflag, N, 512, 1, 512,
                                               nullptr, nullptr, nullptr,
                                               (u16*)d_out, (float*)d_out, 0, 1);
}

// Round 8
// 351.731 us; speedup vs baseline: 1.4359x; 1.0011x over previous
//
#include <hip/hip_runtime.h>
#include <hip/hip_bf16.h>

// ---------------- types & helpers ----------------

typedef __attribute__((ext_vector_type(8)))  short bf16x8;   // 8 bf16 = 4 VGPR
typedef __attribute__((ext_vector_type(16))) float f32x16;   // MFMA 32x32 acc
typedef unsigned short u16;

__device__ __forceinline__ u16 f2bf(float x) {               // RNE fp32->bf16
  union { float f; unsigned u; } c; c.f = x;
  return (u16)((c.u + 0x7fffu + ((c.u >> 16) & 1u)) >> 16);
}
__device__ __forceinline__ float bf2f(u16 u) {               // exact bf16->fp32
  union { unsigned u; float f; } c; c.u = ((unsigned)u) << 16;
  return c.f;
}

// A-pack addressing (fragment-linear, 64-row m-tiles, 32-k ksteps).
// Element (row r, col k) of a matrix with KSQ = Fi/32 ksteps lives at u16 index:
//   slot = ((r>>6)*KSQ + (k>>5))*4 + ((r>>5)&1)*2 + ((k>>4)&1)
//   lane = (r&31) + ((k>>3)&1)*32 ;  j = k&7
//   idx  = slot*512 + lane*8 + j
// GEMM wave reads slot f (f = wm*2 + kc) as one coalesced 16B/lane load.
__device__ __forceinline__ size_t apidx(int r, int k, int KSQ) {
  const int slot = (((r >> 6) * KSQ + (k >> 5)) << 2) + (((r >> 5) & 1) << 1) + ((k >> 4) & 1);
  return ((size_t)slot << 9) + (size_t)(((((k >> 3) & 1) << 5) | (r & 31)) << 3) + (k & 7);
}

// ---------------- sentinel & merged dtype probe ----------------

__global__ void k_sentinel(u16* __restrict__ out, int n) {
  int i = blockIdx.x * blockDim.x + threadIdx.x;
  if (i < n) out[i] = 0x3F00;
}

// block 0: float dtype probe on v; block 1: edge-width probe on ei
__global__ void k_probe(const unsigned* __restrict__ v, int nv, int* __restrict__ vflag,
                        const unsigned* __restrict__ ei, int ne, int* __restrict__ eflag) {
  __shared__ unsigned red[256];
  if (blockIdx.x == 0) {
    int ok = 0;
    for (int i = threadIdx.x; i < nv; i += 256) {
      unsigned lo = v[i] & 0xffffu;
      unsigned ef = (lo >> 7) & 0xffu;
      if (ef >= 115u && ef <= 140u) ok++;
    }
    red[threadIdx.x] = (unsigned)ok;
    __syncthreads();
    for (int s = 128; s > 0; s >>= 1) {
      if (threadIdx.x < s) red[threadIdx.x] += red[threadIdx.x + s];
      __syncthreads();
    }
    if (threadIdx.x == 0) *vflag = ((int)red[0] < nv / 2) ? 1 : 0;
  } else {
    unsigned acc = 0;
    for (int i = threadIdx.x; i < ne; i += 256)
      if (i & 1) acc |= ei[i];
    red[threadIdx.x] = acc;
    __syncthreads();
    for (int s = 128; s > 0; s >>= 1) {
      if (threadIdx.x < s) red[threadIdx.x] |= red[threadIdx.x + s];
      __syncthreads();
    }
    if (threadIdx.x == 0) *eflag = (red[0] == 0u) ? 1 : 0;
  }
}

// ---------------- weight pre-pack (64-wide n-tiles) ----------------
// Pack W[K][Fo] into fragment-linear slots: slot s = (nt*KS + ks)*4 + fb,
// fb = (nblock<<1)|kchunk, lane l holds 8 bf16:
//   W[ks*32 + (fb&1)*16 + (l>>5)*8 + j][nt*64 + (fb>>1)*32 + (l&31)].
__global__ void k_wpack(const void* __restrict__ W, const int* __restrict__ wflagp,
                        int K, int Fo, u16* __restrict__ dstHi, u16* __restrict__ dstLo) {
  const int t = blockIdx.x * 256 + threadIdx.x;
  const int KS = K >> 5;
  const int total = (Fo >> 6) * KS * 4;
  const int s = t >> 6;
  if (s >= total) return;
  const int lane = t & 63;
  const int fb = s & 3;
  const int sk = s >> 2;
  const int ks = sk % KS;
  const int nt = sk / KS;
  const int col = (nt << 6) + ((fb >> 1) << 5) + (lane & 31);
  const int row = (ks << 5) + ((fb & 1) << 4) + ((lane >> 5) << 3);
  const int wflag = *wflagp;
  bf16x8 hi;
  if (wflag) {
    const float* Wf = (const float*)W;
    bf16x8 lo;
#pragma unroll
    for (int j = 0; j < 8; j++) {
      float wv = Wf[(size_t)(row + j) * Fo + col];
      u16 h = f2bf(wv);
      hi[j] = (short)h;
      lo[j] = (short)f2bf(wv - bf2f(h));
    }
    *(bf16x8*)(dstLo + (size_t)s * 512 + lane * 8) = lo;
  } else {
    const u16* Wb = (const u16*)W;
#pragma unroll
    for (int j = 0; j < 8; j++)
      hi[j] = (short)Wb[(size_t)(row + j) * Fo + col];
  }
  *(bf16x8*)(dstHi + (size_t)s * 512 + lane * 8) = hi;
}

// ---------------- preprocessing ----------------

__global__ void k_zero(float* __restrict__ deg, int* __restrict__ cnt, int n) {
  int i = blockIdx.x * blockDim.x + threadIdx.x;
  if (i < n) { deg[i] = 0.0f; cnt[i] = 0; }
}

__global__ void k_decode(const void* __restrict__ ei, const int* __restrict__ eflag,
                         int E, int N, int* __restrict__ rowi, int* __restrict__ coli,
                         float* __restrict__ deg, int* __restrict__ cnt) {
  int e = blockIdx.x * blockDim.x + threadIdx.x;
  if (e >= E) return;
  int f = *eflag;
  int r, c;
  if (f) {
    const long long* q = (const long long*)ei;
    r = (int)q[e]; c = (int)q[e + E];
  } else {
    const int* q = (const int*)ei;
    r = q[e]; c = q[e + E];
  }
  r = min(max(r, 0), N - 1);
  c = min(max(c, 0), N - 1);
  rowi[e] = r; coli[e] = c;
  atomicAdd(&deg[r], 1.0f);
  atomicAdd(&cnt[c], 1);
}

__global__ void k_dis(const float* __restrict__ deg, float* __restrict__ dis, int n) {
  int i = blockIdx.x * blockDim.x + threadIdx.x;
  if (i < n) {
    float d = deg[i];
    dis[i] = (d > 0.f) ? rsqrtf(d) : 0.f;
  }
}

// 1024-thread shuffle-based scan
__global__ __launch_bounds__(1024) void k_scan(const int* __restrict__ cnt,
                                               int* __restrict__ colPtr,
                                               int* __restrict__ cursor, int n) {
  __shared__ int ws[16];
  const int t = threadIdx.x;
  const int lane = t & 63;
  const int w = t >> 6;
  int carry = 0;
  for (int base = 0; base < n; base += 1024) {
    int i = base + t;
    int v = (i < n) ? cnt[i] : 0;
    int x = v;
#pragma unroll
    for (int off = 1; off < 64; off <<= 1) {
      int y = __shfl_up(x, off);
      if (lane >= off) x += y;
    }
    if (lane == 63) ws[w] = x;
    __syncthreads();
    if (w == 0) {
      int sv = (lane < 16) ? ws[lane] : 0;
#pragma unroll
      for (int off = 1; off < 16; off <<= 1) {
        int y = __shfl_up(sv, off);
        if (lane >= off) sv += y;
      }
      if (lane < 16) ws[lane] = sv;
    }
    __syncthreads();
    int woff = (w == 0) ? 0 : ws[w - 1];
    int incl = carry + woff + x;
    if (i < n) { colPtr[i + 1] = incl; cursor[i] = incl - v; }
    int tot = ws[15];
    __syncthreads();
    carry += tot;
  }
  if (t == 0) colPtr[0] = 0;
}

__global__ void k_place(const int* __restrict__ rowi, const int* __restrict__ coli,
                        const float* __restrict__ dis, int* __restrict__ cursor,
                        int* __restrict__ srcRow, float* __restrict__ srcW, int E) {
  int e = blockIdx.x * blockDim.x + threadIdx.x;
  if (e >= E) return;
  int r = rowi[e], c = coli[e];
  float wv = -dis[r] * dis[c];
  int pos = atomicAdd(&cursor[c], 1);
  srcRow[pos] = r;
  srcW[pos] = wv;
}

// v (bf16 or fp32) -> fp32 row-major plane + hi/lo A-PACK planes (Fi=128)
__global__ void k_convert(const void* __restrict__ v, const int* __restrict__ vflag,
                          float* __restrict__ xf, u16* __restrict__ xh,
                          u16* __restrict__ xl, int n4) {
  int i = blockIdx.x * blockDim.x + threadIdx.x;
  if (i >= n4) return;
  float val[4];
  if (*vflag) {
    float4 t = ((const float4*)v)[i];
    val[0] = t.x; val[1] = t.y; val[2] = t.z; val[3] = t.w;
  } else {
    ushort4 t = ((const ushort4*)v)[i];
    val[0] = bf2f(t.x); val[1] = bf2f(t.y); val[2] = bf2f(t.z); val[3] = bf2f(t.w);
  }
  float4 fo; ushort4 ho, lo;
  u16 h;
  h = f2bf(val[0]); ho.x = h; lo.x = f2bf(val[0] - bf2f(h)); fo.x = val[0];
  h = f2bf(val[1]); ho.y = h; lo.y = f2bf(val[1] - bf2f(h)); fo.y = val[1];
  h = f2bf(val[2]); ho.z = h; lo.z = f2bf(val[2] - bf2f(h)); fo.z = val[2];
  h = f2bf(val[3]); ho.w = h; lo.w = f2bf(val[3] - bf2f(h)); fo.w = val[3];
  ((float4*)xf)[i] = fo;
  const int r  = i >> 5;            // 32 groups of 4 per 128-col row
  const int k0 = (i & 31) << 2;
  const size_t pi = apidx(r, k0, 4);   // k0%8 in {0,4} -> 8B-aligned
  *(ushort4*)(xh + pi) = ho;
  *(ushort4*)(xl + pi) = lo;
}

// ---------------- propagation F=128 (wave-per-node, paired edges, 4-deep) ----------------
__global__ __launch_bounds__(256) void k_prop128(
    const float* __restrict__ z, const float* __restrict__ base,
    float* __restrict__ outF, u16* __restrict__ outH, u16* __restrict__ outL,
    const int* __restrict__ colPtr, const int* __restrict__ srcRow,
    const float* __restrict__ srcW, int N, float alpha, float beta) {
  const int lane = threadIdx.x & 63;
  const int c = blockIdx.x * 4 + (threadIdx.x >> 6);
  if (c >= N) return;
  const int half = lane >> 5;          // edge parity this lane accumulates
  const int li = lane & 31;            // column group: cols 4*li..4*li+3
  const int s = colPtr[c], e = colPtr[c + 1];
  float4 accA = make_float4(0.f, 0.f, 0.f, 0.f);
  float4 accB = make_float4(0.f, 0.f, 0.f, 0.f);
  float4 accC = make_float4(0.f, 0.f, 0.f, 0.f);
  float4 accD = make_float4(0.f, 0.f, 0.f, 0.f);

  for (int j0 = s; j0 < e; j0 += 64) {
    const int take = min(64, e - j0);
    int rI = 0; float wI = 0.f;
    if (j0 + lane < e) { rI = srcRow[j0 + lane]; wI = srcW[j0 + lane]; }
    int jj = 0;
    for (; jj + 8 <= take; jj += 8) {          // 4 pairs (8 edges) per iter
      int   ra = __shfl(rI, jj + half);
      float wa = __shfl(wI, jj + half);
      int   rb = __shfl(rI, jj + 2 + half);
      float wb = __shfl(wI, jj + 2 + half);
      int   rc = __shfl(rI, jj + 4 + half);
      float wc = __shfl(wI, jj + 4 + half);
      int   rd = __shfl(rI, jj + 6 + half);
      float wd = __shfl(wI, jj + 6 + half);
      float4 za = *(const float4*)(z + (size_t)ra * 128 + li * 4);
      float4 zb = *(const float4*)(z + (size_t)rb * 128 + li * 4);
      float4 zc = *(const float4*)(z + (size_t)rc * 128 + li * 4);
      float4 zd = *(const float4*)(z + (size_t)rd * 128 + li * 4);
      accA.x = fmaf(wa, za.x, accA.x); accA.y = fmaf(wa, za.y, accA.y);
      accA.z = fmaf(wa, za.z, accA.z); accA.w = fmaf(wa, za.w, accA.w);
      accB.x = fmaf(wb, zb.x, accB.x); accB.y = fmaf(wb, zb.y, accB.y);
      accB.z = fmaf(wb, zb.z, accB.z); accB.w = fmaf(wb, zb.w, accB.w);
      accC.x = fmaf(wc, zc.x, accC.x); accC.y = fmaf(wc, zc.y, accC.y);
      accC.z = fmaf(wc, zc.z, accC.z); accC.w = fmaf(wc, zc.w, accC.w);
      accD.x = fmaf(wd, zd.x, accD.x); accD.y = fmaf(wd, zd.y, accD.y);
      accD.z = fmaf(wd, zd.z, accD.z); accD.w = fmaf(wd, zd.w, accD.w);
    }
    for (; jj < take; jj += 2) {               // tail: guarded lanes give w=0
      int   ra = __shfl(rI, jj + half);
      float wa = __shfl(wI, jj + half);
      float4 za = *(const float4*)(z + (size_t)ra * 128 + li * 4);
      accA.x = fmaf(wa, za.x, accA.x); accA.y = fmaf(wa, za.y, accA.y);
      accA.z = fmaf(wa, za.z, accA.z); accA.w = fmaf(wa, za.w, accA.w);
    }
  }

  float4 acc;
  acc.x = (accA.x + accB.x) + (accC.x + accD.x);
  acc.y = (accA.y + accB.y) + (accC.y + accD.y);
  acc.z = (accA.z + accB.z) + (accC.z + accD.z);
  acc.w = (accA.w + accB.w) + (accC.w + accD.w);
  acc.x += __shfl_xor(acc.x, 32);
  acc.y += __shfl_xor(acc.y, 32);
  acc.z += __shfl_xor(acc.z, 32);
  acc.w += __shfl_xor(acc.w, 32);

  if (lane < 32) {
    float vv[4] = {alpha * acc.x, alpha * acc.y, alpha * acc.z, alpha * acc.w};
    const size_t o = (size_t)c * 128 + li * 4;
    if (base != nullptr) {
      float4 b = *(const float4*)(base + o);
      vv[0] = fmaf(beta, b.x, vv[0]); vv[1] = fmaf(beta, b.y, vv[1]);
      vv[2] = fmaf(beta, b.z, vv[2]); vv[3] = fmaf(beta, b.w, vv[3]);
    }
    if (outF) *(float4*)(outF + o) = make_float4(vv[0], vv[1], vv[2], vv[3]);
    ushort4 ho, lo;
    u16 h;
    h = f2bf(vv[0]); ho.x = h; lo.x = f2bf(vv[0] - bf2f(h));
    h = f2bf(vv[1]); ho.y = h; lo.y = f2bf(vv[1] - bf2f(h));
    h = f2bf(vv[2]); ho.z = h; lo.z = f2bf(vv[2] - bf2f(h));
    h = f2bf(vv[3]); ho.w = h; lo.w = f2bf(vv[3] - bf2f(h));
    const size_t pi = apidx(c, li << 2, 4);    // A-pack, Fi=128
    *(ushort4*)(outH + pi) = ho;
    *(ushort4*)(outL + pi) = lo;
  }
}

// ---------------- propagation F=256 (wave-per-node, full-row float4) ----------------
__global__ __launch_bounds__(256) void k_prop256(
    const float* __restrict__ z, const float* __restrict__ base,
    float* __restrict__ outF, u16* __restrict__ outH, u16* __restrict__ outL,
    const int* __restrict__ colPtr, const int* __restrict__ srcRow,
    const float* __restrict__ srcW, int N, float alpha, float beta) {
  const int lane = threadIdx.x & 63;
  const int c = blockIdx.x * 4 + (threadIdx.x >> 6);
  if (c >= N) return;
  const int s = colPtr[c], e = colPtr[c + 1];
  float4 accA = make_float4(0.f, 0.f, 0.f, 0.f);
  float4 accB = make_float4(0.f, 0.f, 0.f, 0.f);

  for (int j0 = s; j0 < e; j0 += 64) {
    const int take = min(64, e - j0);
    int rI = 0; float wI = 0.f;
    if (j0 + lane < e) { rI = srcRow[j0 + lane]; wI = srcW[j0 + lane]; }
    int jj = 0;
    for (; jj + 4 <= take; jj += 4) {
      int   r0 = __shfl(rI, jj),     r1 = __shfl(rI, jj + 1);
      int   r2 = __shfl(rI, jj + 2), r3 = __shfl(rI, jj + 3);
      float w0 = __shfl(wI, jj),     w1 = __shfl(wI, jj + 1);
      float w2 = __shfl(wI, jj + 2), w3 = __shfl(wI, jj + 3);
      float4 z0 = *(const float4*)(z + (size_t)r0 * 256 + lane * 4);
      float4 z1 = *(const float4*)(z + (size_t)r1 * 256 + lane * 4);
      float4 z2 = *(const float4*)(z + (size_t)r2 * 256 + lane * 4);
      float4 z3 = *(const float4*)(z + (size_t)r3 * 256 + lane * 4);
      accA.x = fmaf(w0, z0.x, accA.x); accA.y = fmaf(w0, z0.y, accA.y);
      accA.z = fmaf(w0, z0.z, accA.z); accA.w = fmaf(w0, z0.w, accA.w);
      accB.x = fmaf(w1, z1.x, accB.x); accB.y = fmaf(w1, z1.y, accB.y);
      accB.z = fmaf(w1, z1.z, accB.z); accB.w = fmaf(w1, z1.w, accB.w);
      accA.x = fmaf(w2, z2.x, accA.x); accA.y = fmaf(w2, z2.y, accA.y);
      accA.z = fmaf(w2, z2.z, accA.z); accA.w = fmaf(w2, z2.w, accA.w);
      accB.x = fmaf(w3, z3.x, accB.x); accB.y = fmaf(w3, z3.y, accB.y);
      accB.z = fmaf(w3, z3.z, accB.z); accB.w = fmaf(w3, z3.w, accB.w);
    }
    for (; jj < take; jj++) {
      int   r = __shfl(rI, jj);
      float w = __shfl(wI, jj);
      float4 zt = *(const float4*)(z + (size_t)r * 256 + lane * 4);
      accA.x = fmaf(w, zt.x, accA.x); accA.y = fmaf(w, zt.y, accA.y);
      accA.z = fmaf(w, zt.z, accA.z); accA.w = fmaf(w, zt.w, accA.w);
    }
  }

  float vv[4] = {alpha * (accA.x + accB.x), alpha * (accA.y + accB.y),
                 alpha * (accA.z + accB.z), alpha * (accA.w + accB.w)};
  const size_t o = (size_t)c * 256 + lane * 4;
  if (base != nullptr) {
    float4 b = *(const float4*)(base + o);
    vv[0] = fmaf(beta, b.x, vv[0]); vv[1] = fmaf(beta, b.y, vv[1]);
    vv[2] = fmaf(beta, b.z, vv[2]); vv[3] = fmaf(beta, b.w, vv[3]);
  }
  if (outF) *(float4*)(outF + o) = make_float4(vv[0], vv[1], vv[2], vv[3]);
  ushort4 ho, lo;
  u16 h;
  h = f2bf(vv[0]); ho.x = h; lo.x = f2bf(vv[0] - bf2f(h));
  h = f2bf(vv[1]); ho.y = h; lo.y = f2bf(vv[1] - bf2f(h));
  h = f2bf(vv[2]); ho.z = h; lo.z = f2bf(vv[2] - bf2f(h));
  h = f2bf(vv[3]); ho.w = h; lo.w = f2bf(vv[3] - bf2f(h));
  const size_t pi = apidx(c, lane << 2, 8);    // A-pack, Fi=256
  *(ushort4*)(outH + pi) = ho;
  *(ushort4*)(outL + pi) = lo;
}

// ---------------- MFMA GEMM (LDS-FREE, barrier-free, XCD swizzle) ----------------
// C[N,Fo] = maybe_relu( [A0|A1|A2] @ W + b ).
// BOTH operands pre-packed fragment-linear in global memory (A by the
// producers' epilogues, W by k_wpack) -> each fragment is one coalesced
// 16B/lane global load DIRECT TO VGPR. No LDS. No __syncthreads.
// Rationale (r2/r3/r5/r6/r7): every LDS+barrier variant pinned at ~50us =
// ~1070 cyc/kstep/CU; the per-kstep vmcnt(0)+barrier convoy prevented
// inter-block overlap. Removing the sync lets waves run free; the compiler
// hoists next-kstep loads over MFMAs; cross-wave frag sharing hits L1.
// C/D mapping (verified): col = lane&31, row = (reg&3)+8*(reg>>2)+4*(lane>>5).
// headSplit: Fo=512 fused [mu|std] -> two N x 256 outputs at d_out, d_out+N*256.
__global__ __launch_bounds__(256, 4) void k_gemm_mfma(
    const u16* __restrict__ a0h, const u16* __restrict__ a0l,
    const u16* __restrict__ a1h, const u16* __restrict__ a1l,
    const u16* __restrict__ a2h, const u16* __restrict__ a2l,
    const u16* __restrict__ packHi, const u16* __restrict__ packLo,
    const void* __restrict__ bias, const void* __restrict__ bias2,
    const int* __restrict__ wflagp,
    int N, int Fi, int NQ, int Fo,
    float* __restrict__ outF, u16* __restrict__ outH, u16* __restrict__ outL,
    u16* __restrict__ outB16, float* __restrict__ outB32, int relu, int headSplit) {
  const int wflag = *wflagp;
  const int tid  = threadIdx.x;
  const int lane = tid & 63;
  const int w    = tid >> 6;
  const int wm   = w >> 1;
  const int wn   = w & 1;

  // chunked-bijective XCD swizzle (m204): orig id -> contiguous chunk per XCD
  const int gx = gridDim.x;
  int wg = blockIdx.x + gx * blockIdx.y;
  {
    const int nwg = gx * gridDim.y;
    const int q = nwg >> 3, r = nwg & 7;
    const int xcd = wg & 7;
    const int idx = wg >> 3;
    wg = (xcd < r ? xcd * (q + 1) : r * (q + 1) + (xcd - r) * q) + idx;
  }
  const int nt = wg % gx;
  const int mt = wg / gx;
  const int n0 = nt << 6;
  const int m0 = mt << 6;
  const int KSQ   = Fi >> 5;
  const int qsh   = __builtin_ctz(KSQ);
  const int qmask = KSQ - 1;
  const int KS    = NQ << qsh;

  const int laneoff = lane << 3;        // lane*8 u16 = 16B

  f32x16 acc = {};

#pragma unroll 2
  for (int ks = 0; ks < KS; ks++) {
    const int q   = ks >> qsh;
    const int ksl = ks & qmask;
    const u16* Ah = (q == 0) ? a0h : (q == 1 ? a1h : a2h);
    const u16* Al = (q == 0) ? a0l : (q == 1 ? a1l : a2l);
    const size_t abase = ((size_t)(mt * KSQ + ksl) << 2) * 512 + (size_t)((wm << 1) * 512) + laneoff;
    const bf16x8 aH0 = *(const bf16x8*)(Ah + abase);
    const bf16x8 aH1 = *(const bf16x8*)(Ah + abase + 512);
    const bf16x8 aL0 = *(const bf16x8*)(Al + abase);
    const bf16x8 aL1 = *(const bf16x8*)(Al + abase + 512);
    const size_t bbase = (((size_t)(nt * KS + ks) << 2) + (wn << 1)) * 512 + laneoff;
    const bf16x8 b0 = *(const bf16x8*)(packHi + bbase);
    const bf16x8 b1 = *(const bf16x8*)(packHi + bbase + 512);

    acc = __builtin_amdgcn_mfma_f32_32x32x16_bf16(aH0, b0, acc, 0, 0, 0);
    acc = __builtin_amdgcn_mfma_f32_32x32x16_bf16(aL0, b0, acc, 0, 0, 0);
    acc = __builtin_amdgcn_mfma_f32_32x32x16_bf16(aH1, b1, acc, 0, 0, 0);
    acc = __builtin_amdgcn_mfma_f32_32x32x16_bf16(aL1, b1, acc, 0, 0, 0);
    if (wflag) {
      const bf16x8 c0 = *(const bf16x8*)(packLo + bbase);
      const bf16x8 c1 = *(const bf16x8*)(packLo + bbase + 512);
      acc = __builtin_amdgcn_mfma_f32_32x32x16_bf16(aH0, c0, acc, 0, 0, 0);
      acc = __builtin_amdgcn_mfma_f32_32x32x16_bf16(aH1, c1, acc, 0, 0, 0);
    }
  }

  // ---- epilogue (single 32x32 frag per wave) ----
  {
    const int ncol = n0 + (wn << 5) + (lane & 31);
    const int KSQo = Fo >> 5;
    int col = ncol;
    const void* bp = bias;
    size_t obase = 0;
    int FoOut = Fo;
    if (headSplit) {
      FoOut = 256;
      if (ncol >= 256) { col = ncol - 256; bp = bias2; obase = (size_t)N * 256; }
    }
    const float bv = wflag ? ((const float*)bp)[col]
                           : bf2f(((const u16*)bp)[col]);
#pragma unroll
    for (int r = 0; r < 16; r++) {
      const int m = m0 + (wm << 5) + (r & 3) + ((r >> 2) << 3) + ((lane >> 5) << 2);
      if (m < N) {
        float vv = acc[r] + bv;
        if (relu) vv = fmaxf(vv, 0.f);
        if (outF) outF[(size_t)m * Fo + ncol] = vv;
        if (outH) {                               // next layer's A-pack
          u16 h = f2bf(vv);
          const size_t pi = apidx(m, ncol, KSQo);
          outH[pi] = h;
          outL[pi] = f2bf(vv - bf2f(h));
        }
        if (outB16) {                             // final output, row-major
          const size_t o = obase + (size_t)m * FoOut + col;
          if (wflag) outB32[o] = vv;
          else       outB16[o] = f2bf(vv);
        }
      }
    }
  }
}

// ---------------- host (kernel launches ONLY) ----------------

static size_t align256(size_t x) { return (x + 255) & ~(size_t)255; }

extern "C" void kernel_launch(void* const* d_in, const int* in_sizes, int n_in,
                              void* d_out, int out_size, void* d_ws, size_t ws_size,
                              hipStream_t stream) {
  const void* v    = d_in[0];
  const void* ei   = d_in[1];
  const void* W1   = d_in[2];
  const void* b1   = d_in[3];
  const void* W2   = d_in[4];
  const void* b2   = d_in[5];
  const void* W3   = d_in[6];
  const void* b3   = d_in[7];
  const void* Wmu  = d_in[8];
  const void* bmu  = d_in[9];
  const void* Wstd = d_in[10];
  const void* bstd = d_in[11];
  (void)n_in; (void)ws_size;

  const int N = in_sizes[0] / 128;   // 10000
  const int E = in_sizes[1] / 2;     // 160000
  const size_t NP = ((size_t)N + 63) & ~(size_t)63;   // pack row bound (64-mult)

  char* base = (char*)d_ws;
  size_t off = 0;
  auto carve = [&](size_t bytes) { void* p = base + off; off = align256(off + bytes); return p; };

  int*   eflag  = (int*)  carve(4);
  int*   vflag  = (int*)  carve(4);
  int*   rowi   = (int*)  carve((size_t)E * 4);
  int*   coli   = (int*)  carve((size_t)E * 4);
  float* deg    = (float*)carve((size_t)N * 4);
  float* dis    = (float*)carve((size_t)N * 4);
  int*   cnt    = (int*)  carve((size_t)N * 4);
  int*   colPtr = (int*)  carve((size_t)(N + 1) * 4);
  int*   cursor = (int*)  carve((size_t)N * 4);
  int*   srcRow = (int*)  carve((size_t)E * 4);
  float* srcW   = (float*)carve((size_t)E * 4);

  // weight packs (hi/lo); heads fused [mu|std] contiguously
  u16* pW1h = (u16*)carve((size_t)384 * 128 * 2);
  u16* pW1l = (u16*)carve((size_t)384 * 128 * 2);
  u16* pW2h = (u16*)carve((size_t)384 * 256 * 2);
  u16* pW2l = (u16*)carve((size_t)384 * 256 * 2);
  u16* pW3h = (u16*)carve((size_t)768 * 512 * 2);
  u16* pW3l = (u16*)carve((size_t)768 * 512 * 2);
  u16* pHh  = (u16*)carve((size_t)2 * 512 * 256 * 2);
  u16* pHl  = (u16*)carve((size_t)2 * 512 * 256 * 2);

  // activation planes: f32 row-major (prop inputs) + hi/lo A-packs (GEMM inputs)
  float* Xf  = (float*)carve(NP * 256 * 4);
  u16*   Xh  = (u16*)  carve(NP * 256 * 2);
  u16*   Xl  = (u16*)  carve(NP * 256 * 2);
  float* Yf  = (float*)carve(NP * 128 * 4);
  u16*   Yh  = (u16*)  carve(NP * 512 * 2);
  u16*   Yl  = (u16*)  carve(NP * 512 * 2);
  float* t1f = (float*)carve(NP * 256 * 4);
  u16*   t1h = (u16*)  carve(NP * 256 * 2);
  u16*   t1l = (u16*)  carve(NP * 256 * 2);
  u16*   t2h = (u16*)  carve(NP * 256 * 2);
  u16*   t2l = (u16*)  carve(NP * 256 * 2);

  // 1) sentinel
  k_sentinel<<<(out_size + 255) / 256, 256, 0, stream>>>((u16*)d_out, out_size);

  // 2) dtype probes (merged)
  k_probe<<<2, 256, 0, stream>>>((const unsigned*)v, 1024, vflag,
                                 (const unsigned*)ei, 2048, eflag);

  // 3) weight pre-pack (64-wide tiles)
  k_wpack<<< 24, 256, 0, stream>>>(W1,   vflag, 384, 128, pW1h, pW1l);
  k_wpack<<< 48, 256, 0, stream>>>(W2,   vflag, 384, 256, pW2h, pW2l);
  k_wpack<<<192, 256, 0, stream>>>(W3,   vflag, 768, 512, pW3h, pW3l);
  k_wpack<<< 64, 256, 0, stream>>>(Wmu,  vflag, 512, 256, pHh,            pHl);
  k_wpack<<< 64, 256, 0, stream>>>(Wstd, vflag, 512, 256, pHh + 131072,   pHl + 131072);

  // 4) graph preprocessing
  k_zero<<<(N + 255) / 256, 256, 0, stream>>>(deg, cnt, N);
  k_decode<<<(E + 255) / 256, 256, 0, stream>>>(ei, eflag, E, N, rowi, coli, deg, cnt);
  k_dis<<<(N + 255) / 256, 256, 0, stream>>>(deg, dis, N);
  k_scan<<<1, 1024, 0, stream>>>(cnt, colPtr, cursor, N);
  k_place<<<(E + 255) / 256, 256, 0, stream>>>(rowi, coli, dis, cursor, srcRow, srcW, E);
  k_convert<<<(N * 128 / 4 + 255) / 256, 256, 0, stream>>>(v, vflag, Xf, Xh, Xl, N * 128 / 4);

  const int gM = (N + 63) / 64;     // 157 m-tiles
  const int gP = (N + 3) / 4;       // wave-per-node prop blocks

  // layer 1: Fi=128 -> Fo=128, X -> Y
  k_prop128<<<gP, 256, 0, stream>>>(Xf, nullptr, t1f, t1h, t1l, colPtr, srcRow, srcW, N, 1.f, 0.f);
  k_prop128<<<gP, 256, 0, stream>>>(t1f, Xf, nullptr, t2h, t2l, colPtr, srcRow, srcW, N, 2.f, -1.f);
  k_gemm_mfma<<<dim3(2, gM), 256, 0, stream>>>(Xh, Xl, t1h, t1l, t2h, t2l, pW1h, pW1l,
                                               b1, b1, vflag, N, 128, 3, 128,
                                               Yf, Yh, Yl, nullptr, nullptr, 1, 0);

  // layer 2: Fi=128 -> Fo=256, Y -> X
  k_prop128<<<gP, 256, 0, stream>>>(Yf, nullptr, t1f, t1h, t1l, colPtr, srcRow, srcW, N, 1.f, 0.f);
  k_prop128<<<gP, 256, 0, stream>>>(t1f, Yf, nullptr, t2h, t2l, colPtr, srcRow, srcW, N, 2.f, -1.f);
  k_gemm_mfma<<<dim3(4, gM), 256, 0, stream>>>(Yh, Yl, t1h, t1l, t2h, t2l, pW2h, pW2l,
                                               b2, b2, vflag, N, 128, 3, 256,
                                               Xf, Xh, Xl, nullptr, nullptr, 1, 0);

  // layer 3: Fi=256 -> Fo=512, X -> Y (packs only; no one reads fp32 x3)
  k_prop256<<<gP, 256, 0, stream>>>(Xf, nullptr, t1f, t1h, t1l, colPtr, srcRow, srcW, N, 1.f, 0.f);
  k_prop256<<<gP, 256, 0, stream>>>(t1f, Xf, nullptr, t2h, t2l, colPtr, srcRow, srcW, N, 2.f, -1.f);
  k_gemm_mfma<<<dim3(8, gM), 256, 0, stream>>>(Xh, Xl, t1h, t1l, t2h, t2l, pW3h, pW3l,
                                               b3, b3, vflag, N, 256, 3, 512,
                                               nullptr, Yh, Yl, nullptr, nullptr, 1, 0);

  // fused heads: x3 (N x 512 pack) @ [Wmu|Wstd] -> mu, std at d_out
  k_gemm_mfma<<<dim3(8, gM), 256, 0, stream>>>(Yh, Yl, nullptr, nullptr, nullptr, nullptr,
                                               pHh, pHl, bmu, bstd, vflag, N, 512, 1, 512,
                                               nullptr, nullptr, nullptr,
                                               (u16*)d_out, (float*)d_out, 0, 1);
}

// Round 9
// 339.955 us; speedup vs baseline: 1.4857x; 1.0346x over previous
//
#include <hip/hip_runtime.h>
#include <hip/hip_bf16.h>

// ---------------- types & helpers ----------------

typedef __attribute__((ext_vector_type(8)))  short bf16x8;   // 8 bf16 = 4 VGPR
typedef __attribute__((ext_vector_type(16))) float f32x16;   // MFMA 32x32 acc
typedef unsigned short u16;

__device__ __forceinline__ u16 f2bf(float x) {               // RNE fp32->bf16
  union { float f; unsigned u; } c; c.f = x;
  return (u16)((c.u + 0x7fffu + ((c.u >> 16) & 1u)) >> 16);
}
__device__ __forceinline__ float bf2f(u16 u) {               // exact bf16->fp32
  union { unsigned u; float f; } c; c.u = ((unsigned)u) << 16;
  return c.f;
}

// A-pack addressing (fragment-linear, 64-row m-tiles, 32-k ksteps).
// Element (row r, col k), KSQ = Fi/32:
//   slot = ((r>>6)*KSQ + (k>>5))*4 + ((r>>5)&1)*2 + ((k>>4)&1)
//   lane = (r&31) + ((k>>3)&1)*32 ;  j = k&7 ;  idx = slot*512 + lane*8 + j
__device__ __forceinline__ size_t apidx(int r, int k, int KSQ) {
  const int slot = (((r >> 6) * KSQ + (k >> 5)) << 2) + (((r >> 5) & 1) << 1) + ((k >> 4) & 1);
  return ((size_t)slot << 9) + (size_t)(((((k >> 3) & 1) << 5) | (r & 31)) << 3) + (k & 7);
}

// ---------------- sentinel ----------------

__global__ void k_sentinel(u16* __restrict__ out, int n) {
  int i = blockIdx.x * blockDim.x + threadIdx.x;
  if (i < n) out[i] = 0x3F00;
}

// ---------------- fused init: dtype probes + zero ----------------
// block 0: v float-dtype probe; block 1: ei width probe; blocks 2..: zero deg/cnt
__global__ void k_init(const unsigned* __restrict__ v, int nv, int* __restrict__ vflag,
                       const unsigned* __restrict__ ei, int ne, int* __restrict__ eflag,
                       float* __restrict__ deg, int* __restrict__ cnt, int n) {
  __shared__ unsigned red[256];
  if (blockIdx.x == 0) {
    int ok = 0;
    for (int i = threadIdx.x; i < nv; i += 256) {
      unsigned lo = v[i] & 0xffffu;
      unsigned ef = (lo >> 7) & 0xffu;
      if (ef >= 115u && ef <= 140u) ok++;
    }
    red[threadIdx.x] = (unsigned)ok;
    __syncthreads();
    for (int s = 128; s > 0; s >>= 1) {
      if (threadIdx.x < s) red[threadIdx.x] += red[threadIdx.x + s];
      __syncthreads();
    }
    if (threadIdx.x == 0) *vflag = ((int)red[0] < nv / 2) ? 1 : 0;
  } else if (blockIdx.x == 1) {
    unsigned acc = 0;
    for (int i = threadIdx.x; i < ne; i += 256)
      if (i & 1) acc |= ei[i];
    red[threadIdx.x] = acc;
    __syncthreads();
    for (int s = 128; s > 0; s >>= 1) {
      if (threadIdx.x < s) red[threadIdx.x] |= red[threadIdx.x + s];
      __syncthreads();
    }
    if (threadIdx.x == 0) *eflag = (red[0] == 0u) ? 1 : 0;
  } else {
    int i = (blockIdx.x - 2) * 256 + threadIdx.x;
    if (i < n) { deg[i] = 0.0f; cnt[i] = 0; }
  }
}

// ---------------- fused pack: 5 weight packs + input convert ----------------
// Weight pack (64-wide n-tiles): slot s = (nt*KS + ks)*4 + fb,
// fb=(nblock<<1)|kchunk, lane l: W[ks*32+(fb&1)*16+(l>>5)*8+j][nt*64+(fb>>1)*32+(l&31)].
__device__ __forceinline__ void wpack_dev(
    const void* __restrict__ W, int wflag, int K, int Fo,
    u16* __restrict__ dstHi, u16* __restrict__ dstLo, int blk, int tid) {
  const int t = blk * 256 + tid;
  const int KS = K >> 5;
  const int total = (Fo >> 6) * KS * 4;
  const int s = t >> 6;
  if (s >= total) return;
  const int lane = t & 63;
  const int fb = s & 3;
  const int sk = s >> 2;
  const int ks = sk % KS;
  const int nt = sk / KS;
  const int col = (nt << 6) + ((fb >> 1) << 5) + (lane & 31);
  const int row = (ks << 5) + ((fb & 1) << 4) + ((lane >> 5) << 3);
  bf16x8 hi;
  if (wflag) {
    const float* Wf = (const float*)W;
    bf16x8 lo;
#pragma unroll
    for (int j = 0; j < 8; j++) {
      float wv = Wf[(size_t)(row + j) * Fo + col];
      u16 h = f2bf(wv);
      hi[j] = (short)h;
      lo[j] = (short)f2bf(wv - bf2f(h));
    }
    *(bf16x8*)(dstLo + (size_t)s * 512 + lane * 8) = lo;
  } else {
    const u16* Wb = (const u16*)W;
#pragma unroll
    for (int j = 0; j < 8; j++)
      hi[j] = (short)Wb[(size_t)(row + j) * Fo + col];
  }
  *(bf16x8*)(dstHi + (size_t)s * 512 + lane * 8) = hi;
}

// boundaries c1..c6 are exclusive prefix block counts for the 6 jobs.
__global__ void k_pack(const void* __restrict__ W1, const void* __restrict__ W2,
                       const void* __restrict__ W3, const void* __restrict__ Wmu,
                       const void* __restrict__ Wstd,
                       u16* pW1h, u16* pW1l, u16* pW2h, u16* pW2l,
                       u16* pW3h, u16* pW3l, u16* pHh, u16* pHl,
                       const void* __restrict__ v, float* __restrict__ xf,
                       u16* __restrict__ xh, u16* __restrict__ xl, int n4,
                       const int* __restrict__ flags,
                       int c1, int c2, int c3, int c4, int c5) {
  const int wflag = flags[1];   // vflag (weights share input dtype)
  const int b = blockIdx.x;
  const int tid = threadIdx.x;
  if (b < c1)      { wpack_dev(W1,   wflag, 384, 128, pW1h, pW1l, b,      tid); return; }
  if (b < c2)      { wpack_dev(W2,   wflag, 384, 256, pW2h, pW2l, b - c1, tid); return; }
  if (b < c3)      { wpack_dev(W3,   wflag, 768, 512, pW3h, pW3l, b - c2, tid); return; }
  if (b < c4)      { wpack_dev(Wmu,  wflag, 512, 256, pHh,           pHl,           b - c3, tid); return; }
  if (b < c5)      { wpack_dev(Wstd, wflag, 512, 256, pHh + 131072,  pHl + 131072,  b - c4, tid); return; }
  // input convert: v (bf16/fp32) -> fp32 row-major + hi/lo A-pack (Fi=128)
  const int i = (b - c5) * 256 + tid;
  if (i >= n4) return;
  float val[4];
  if (wflag) {
    float4 t = ((const float4*)v)[i];
    val[0] = t.x; val[1] = t.y; val[2] = t.z; val[3] = t.w;
  } else {
    ushort4 t = ((const ushort4*)v)[i];
    val[0] = bf2f(t.x); val[1] = bf2f(t.y); val[2] = bf2f(t.z); val[3] = bf2f(t.w);
  }
  float4 fo; ushort4 ho, lo;
  u16 h;
  h = f2bf(val[0]); ho.x = h; lo.x = f2bf(val[0] - bf2f(h)); fo.x = val[0];
  h = f2bf(val[1]); ho.y = h; lo.y = f2bf(val[1] - bf2f(h)); fo.y = val[1];
  h = f2bf(val[2]); ho.z = h; lo.z = f2bf(val[2] - bf2f(h)); fo.z = val[2];
  h = f2bf(val[3]); ho.w = h; lo.w = f2bf(val[3] - bf2f(h)); fo.w = val[3];
  ((float4*)xf)[i] = fo;
  const int r  = i >> 5;
  const int k0 = (i & 31) << 2;
  const size_t pi = apidx(r, k0, 4);
  *(ushort4*)(xh + pi) = ho;
  *(ushort4*)(xl + pi) = lo;
}

// ---------------- preprocessing ----------------

__global__ void k_decode(const void* __restrict__ ei, const int* __restrict__ eflag,
                         int E, int N, int* __restrict__ rowi, int* __restrict__ coli,
                         float* __restrict__ deg, int* __restrict__ cnt) {
  int e = blockIdx.x * blockDim.x + threadIdx.x;
  if (e >= E) return;
  int f = *eflag;
  int r, c;
  if (f) {
    const long long* q = (const long long*)ei;
    r = (int)q[e]; c = (int)q[e + E];
  } else {
    const int* q = (const int*)ei;
    r = q[e]; c = q[e + E];
  }
  r = min(max(r, 0), N - 1);
  c = min(max(c, 0), N - 1);
  rowi[e] = r; coli[e] = c;
  atomicAdd(&deg[r], 1.0f);
  atomicAdd(&cnt[c], 1);
}

// 1024-thread shuffle scan (cnt -> colPtr/cursor) fused with dis = rsqrt(deg)
__global__ __launch_bounds__(1024) void k_scan(const int* __restrict__ cnt,
                                               int* __restrict__ colPtr,
                                               int* __restrict__ cursor,
                                               const float* __restrict__ deg,
                                               float* __restrict__ dis, int n) {
  __shared__ int ws[16];
  const int t = threadIdx.x;
  const int lane = t & 63;
  const int w = t >> 6;
  int carry = 0;
  for (int base = 0; base < n; base += 1024) {
    int i = base + t;
    int v = (i < n) ? cnt[i] : 0;
    if (i < n) {
      float d = deg[i];
      dis[i] = (d > 0.f) ? rsqrtf(d) : 0.f;
    }
    int x = v;
#pragma unroll
    for (int off = 1; off < 64; off <<= 1) {
      int y = __shfl_up(x, off);
      if (lane >= off) x += y;
    }
    if (lane == 63) ws[w] = x;
    __syncthreads();
    if (w == 0) {
      int sv = (lane < 16) ? ws[lane] : 0;
#pragma unroll
      for (int off = 1; off < 16; off <<= 1) {
        int y = __shfl_up(sv, off);
        if (lane >= off) sv += y;
      }
      if (lane < 16) ws[lane] = sv;
    }
    __syncthreads();
    int woff = (w == 0) ? 0 : ws[w - 1];
    int incl = carry + woff + x;
    if (i < n) { colPtr[i + 1] = incl; cursor[i] = incl - v; }
    int tot = ws[15];
    __syncthreads();
    carry += tot;
  }
  if (t == 0) colPtr[0] = 0;
}

// place: CSC edge list as packed int2 {srcRow, w-bits} -> one 8B load in props
__global__ void k_place(const int* __restrict__ rowi, const int* __restrict__ coli,
                        const float* __restrict__ dis, int* __restrict__ cursor,
                        int2* __restrict__ edges, int E) {
  int e = blockIdx.x * blockDim.x + threadIdx.x;
  if (e >= E) return;
  int r = rowi[e], c = coli[e];
  float wv = -dis[r] * dis[c];
  int pos = atomicAdd(&cursor[c], 1);
  edges[pos] = make_int2(r, __float_as_int(wv));
}

// ---------------- propagation F=128 (wave-per-node, paired edges, 4-deep) ----------------
__global__ __launch_bounds__(256) void k_prop128(
    const float* __restrict__ z, const float* __restrict__ base,
    float* __restrict__ outF, u16* __restrict__ outH, u16* __restrict__ outL,
    const int* __restrict__ colPtr, const int2* __restrict__ edges,
    int N, float alpha, float beta) {
  const int lane = threadIdx.x & 63;
  const int c = blockIdx.x * 4 + (threadIdx.x >> 6);
  if (c >= N) return;
  const int half = lane >> 5;
  const int li = lane & 31;
  const int s = colPtr[c], e = colPtr[c + 1];
  float4 accA = make_float4(0.f, 0.f, 0.f, 0.f);
  float4 accB = make_float4(0.f, 0.f, 0.f, 0.f);
  float4 accC = make_float4(0.f, 0.f, 0.f, 0.f);
  float4 accD = make_float4(0.f, 0.f, 0.f, 0.f);

  for (int j0 = s; j0 < e; j0 += 64) {
    const int take = min(64, e - j0);
    int rI = 0; float wI = 0.f;
    if (j0 + lane < e) {
      int2 ew = edges[j0 + lane];
      rI = ew.x; wI = __int_as_float(ew.y);
    }
    int jj = 0;
    for (; jj + 8 <= take; jj += 8) {          // 4 pairs (8 edges) per iter
      int   ra = __shfl(rI, jj + half);
      float wa = __shfl(wI, jj + half);
      int   rb = __shfl(rI, jj + 2 + half);
      float wb = __shfl(wI, jj + 2 + half);
      int   rc = __shfl(rI, jj + 4 + half);
      float wc = __shfl(wI, jj + 4 + half);
      int   rd = __shfl(rI, jj + 6 + half);
      float wd = __shfl(wI, jj + 6 + half);
      float4 za = *(const float4*)(z + (size_t)ra * 128 + li * 4);
      float4 zb = *(const float4*)(z + (size_t)rb * 128 + li * 4);
      float4 zc = *(const float4*)(z + (size_t)rc * 128 + li * 4);
      float4 zd = *(const float4*)(z + (size_t)rd * 128 + li * 4);
      accA.x = fmaf(wa, za.x, accA.x); accA.y = fmaf(wa, za.y, accA.y);
      accA.z = fmaf(wa, za.z, accA.z); accA.w = fmaf(wa, za.w, accA.w);
      accB.x = fmaf(wb, zb.x, accB.x); accB.y = fmaf(wb, zb.y, accB.y);
      accB.z = fmaf(wb, zb.z, accB.z); accB.w = fmaf(wb, zb.w, accB.w);
      accC.x = fmaf(wc, zc.x, accC.x); accC.y = fmaf(wc, zc.y, accC.y);
      accC.z = fmaf(wc, zc.z, accC.z); accC.w = fmaf(wc, zc.w, accC.w);
      accD.x = fmaf(wd, zd.x, accD.x); accD.y = fmaf(wd, zd.y, accD.y);
      accD.z = fmaf(wd, zd.z, accD.z); accD.w = fmaf(wd, zd.w, accD.w);
    }
    for (; jj < take; jj += 2) {               // tail: guarded lanes give w=0
      int   ra = __shfl(rI, jj + half);
      float wa = __shfl(wI, jj + half);
      float4 za = *(const float4*)(z + (size_t)ra * 128 + li * 4);
      accA.x = fmaf(wa, za.x, accA.x); accA.y = fmaf(wa, za.y, accA.y);
      accA.z = fmaf(wa, za.z, accA.z); accA.w = fmaf(wa, za.w, accA.w);
    }
  }

  float4 acc;
  acc.x = (accA.x + accB.x) + (accC.x + accD.x);
  acc.y = (accA.y + accB.y) + (accC.y + accD.y);
  acc.z = (accA.z + accB.z) + (accC.z + accD.z);
  acc.w = (accA.w + accB.w) + (accC.w + accD.w);
  acc.x += __shfl_xor(acc.x, 32);
  acc.y += __shfl_xor(acc.y, 32);
  acc.z += __shfl_xor(acc.z, 32);
  acc.w += __shfl_xor(acc.w, 32);

  if (lane < 32) {
    float vv[4] = {alpha * acc.x, alpha * acc.y, alpha * acc.z, alpha * acc.w};
    const size_t o = (size_t)c * 128 + li * 4;
    if (base != nullptr) {
      float4 b = *(const float4*)(base + o);
      vv[0] = fmaf(beta, b.x, vv[0]); vv[1] = fmaf(beta, b.y, vv[1]);
      vv[2] = fmaf(beta, b.z, vv[2]); vv[3] = fmaf(beta, b.w, vv[3]);
    }
    if (outF) *(float4*)(outF + o) = make_float4(vv[0], vv[1], vv[2], vv[3]);
    ushort4 ho, lo;
    u16 h;
    h = f2bf(vv[0]); ho.x = h; lo.x = f2bf(vv[0] - bf2f(h));
    h = f2bf(vv[1]); ho.y = h; lo.y = f2bf(vv[1] - bf2f(h));
    h = f2bf(vv[2]); ho.z = h; lo.z = f2bf(vv[2] - bf2f(h));
    h = f2bf(vv[3]); ho.w = h; lo.w = f2bf(vv[3] - bf2f(h));
    const size_t pi = apidx(c, li << 2, 4);    // A-pack, Fi=128
    *(ushort4*)(outH + pi) = ho;
    *(ushort4*)(outL + pi) = lo;
  }
}

// ---------------- propagation F=256 (wave-per-node, full-row float4, 8-deep) ----------------
__global__ __launch_bounds__(256) void k_prop256(
    const float* __restrict__ z, const float* __restrict__ base,
    float* __restrict__ outF, u16* __restrict__ outH, u16* __restrict__ outL,
    const int* __restrict__ colPtr, const int2* __restrict__ edges,
    int N, float alpha, float beta) {
  const int lane = threadIdx.x & 63;
  const int c = blockIdx.x * 4 + (threadIdx.x >> 6);
  if (c >= N) return;
  const int s = colPtr[c], e = colPtr[c + 1];
  float4 accA = make_float4(0.f, 0.f, 0.f, 0.f);
  float4 accB = make_float4(0.f, 0.f, 0.f, 0.f);
  float4 accC = make_float4(0.f, 0.f, 0.f, 0.f);
  float4 accD = make_float4(0.f, 0.f, 0.f, 0.f);

  for (int j0 = s; j0 < e; j0 += 64) {
    const int take = min(64, e - j0);
    int rI = 0; float wI = 0.f;
    if (j0 + lane < e) {
      int2 ew = edges[j0 + lane];
      rI = ew.x; wI = __int_as_float(ew.y);
    }
    int jj = 0;
    for (; jj + 8 <= take; jj += 8) {          // 8 gathers in flight
      int r0 = __shfl(rI, jj),     r1 = __shfl(rI, jj + 1);
      int r2 = __shfl(rI, jj + 2), r3 = __shfl(rI, jj + 3);
      int r4 = __shfl(rI, jj + 4), r5 = __shfl(rI, jj + 5);
      int r6 = __shfl(rI, jj + 6), r7 = __shfl(rI, jj + 7);
      float w0 = __shfl(wI, jj),     w1 = __shfl(wI, jj + 1);
      float w2 = __shfl(wI, jj + 2), w3 = __shfl(wI, jj + 3);
      float w4 = __shfl(wI, jj + 4), w5 = __shfl(wI, jj + 5);
      float w6 = __shfl(wI, jj + 6), w7 = __shfl(wI, jj + 7);
      float4 z0 = *(const float4*)(z + (size_t)r0 * 256 + lane * 4);
      float4 z1 = *(const float4*)(z + (size_t)r1 * 256 + lane * 4);
      float4 z2 = *(const float4*)(z + (size_t)r2 * 256 + lane * 4);
      float4 z3 = *(const float4*)(z + (size_t)r3 * 256 + lane * 4);
      float4 z4 = *(const float4*)(z + (size_t)r4 * 256 + lane * 4);
      float4 z5 = *(const float4*)(z + (size_t)r5 * 256 + lane * 4);
      float4 z6 = *(const float4*)(z + (size_t)r6 * 256 + lane * 4);
      float4 z7 = *(const float4*)(z + (size_t)r7 * 256 + lane * 4);
      accA.x = fmaf(w0, z0.x, accA.x); accA.y = fmaf(w0, z0.y, accA.y);
      accA.z = fmaf(w0, z0.z, accA.z); accA.w = fmaf(w0, z0.w, accA.w);
      accB.x = fmaf(w1, z1.x, accB.x); accB.y = fmaf(w1, z1.y, accB.y);
      accB.z = fmaf(w1, z1.z, accB.z); accB.w = fmaf(w1, z1.w, accB.w);
      accC.x = fmaf(w2, z2.x, accC.x); accC.y = fmaf(w2, z2.y, accC.y);
      accC.z = fmaf(w2, z2.z, accC.z); accC.w = fmaf(w2, z2.w, accC.w);
      accD.x = fmaf(w3, z3.x, accD.x); accD.y = fmaf(w3, z3.y, accD.y);
      accD.z = fmaf(w3, z3.z, accD.z); accD.w = fmaf(w3, z3.w, accD.w);
      accA.x = fmaf(w4, z4.x, accA.x); accA.y = fmaf(w4, z4.y, accA.y);
      accA.z = fmaf(w4, z4.z, accA.z); accA.w = fmaf(w4, z4.w, accA.w);
      accB.x = fmaf(w5, z5.x, accB.x); accB.y = fmaf(w5, z5.y, accB.y);
      accB.z = fmaf(w5, z5.z, accB.z); accB.w = fmaf(w5, z5.w, accB.w);
      accC.x = fmaf(w6, z6.x, accC.x); accC.y = fmaf(w6, z6.y, accC.y);
      accC.z = fmaf(w6, z6.z, accC.z); accC.w = fmaf(w6, z6.w, accC.w);
      accD.x = fmaf(w7, z7.x, accD.x); accD.y = fmaf(w7, z7.y, accD.y);
      accD.z = fmaf(w7, z7.z, accD.z); accD.w = fmaf(w7, z7.w, accD.w);
    }
    for (; jj < take; jj++) {
      int   r = __shfl(rI, jj);
      float w = __shfl(wI, jj);
      float4 zt = *(const float4*)(z + (size_t)r * 256 + lane * 4);
      accA.x = fmaf(w, zt.x, accA.x); accA.y = fmaf(w, zt.y, accA.y);
      accA.z = fmaf(w, zt.z, accA.z); accA.w = fmaf(w, zt.w, accA.w);
    }
  }

  float vv[4] = {alpha * ((accA.x + accB.x) + (accC.x + accD.x)),
                 alpha * ((accA.y + accB.y) + (accC.y + accD.y)),
                 alpha * ((accA.z + accB.z) + (accC.z + accD.z)),
                 alpha * ((accA.w + accB.w) + (accC.w + accD.w))};
  const size_t o = (size_t)c * 256 + lane * 4;
  if (base != nullptr) {
    float4 b = *(const float4*)(base + o);
    vv[0] = fmaf(beta, b.x, vv[0]); vv[1] = fmaf(beta, b.y, vv[1]);
    vv[2] = fmaf(beta, b.z, vv[2]); vv[3] = fmaf(beta, b.w, vv[3]);
  }
  if (outF) *(float4*)(outF + o) = make_float4(vv[0], vv[1], vv[2], vv[3]);
  ushort4 ho, lo;
  u16 h;
  h = f2bf(vv[0]); ho.x = h; lo.x = f2bf(vv[0] - bf2f(h));
  h = f2bf(vv[1]); ho.y = h; lo.y = f2bf(vv[1] - bf2f(h));
  h = f2bf(vv[2]); ho.z = h; lo.z = f2bf(vv[2] - bf2f(h));
  h = f2bf(vv[3]); ho.w = h; lo.w = f2bf(vv[3] - bf2f(h));
  const size_t pi = apidx(c, lane << 2, 8);    // A-pack, Fi=256
  *(ushort4*)(outH + pi) = ho;
  *(ushort4*)(outL + pi) = lo;
}

// ---------------- MFMA GEMM (LDS-FREE, barrier-free, XCD swizzle) ----------------
// Best-measured structure (r8: 46.3us L3, 341 TF ~= m97-ladder at this size).
// BOTH operands pre-packed fragment-linear in global; fragments load direct
// to VGPR as coalesced 16B/lane; no LDS, no barriers. Kept frozen this round.
// C/D mapping (verified): col = lane&31, row = (reg&3)+8*(reg>>2)+4*(lane>>5).
__global__ __launch_bounds__(256, 4) void k_gemm_mfma(
    const u16* __restrict__ a0h, const u16* __restrict__ a0l,
    const u16* __restrict__ a1h, const u16* __restrict__ a1l,
    const u16* __restrict__ a2h, const u16* __restrict__ a2l,
    const u16* __restrict__ packHi, const u16* __restrict__ packLo,
    const void* __restrict__ bias, const void* __restrict__ bias2,
    const int* __restrict__ wflagp,
    int N, int Fi, int NQ, int Fo,
    float* __restrict__ outF, u16* __restrict__ outH, u16* __restrict__ outL,
    u16* __restrict__ outB16, float* __restrict__ outB32, int relu, int headSplit) {
  const int wflag = *wflagp;
  const int tid  = threadIdx.x;
  const int lane = tid & 63;
  const int w    = tid >> 6;
  const int wm   = w >> 1;
  const int wn   = w & 1;

  const int gx = gridDim.x;
  int wg = blockIdx.x + gx * blockIdx.y;
  {
    const int nwg = gx * gridDim.y;
    const int q = nwg >> 3, r = nwg & 7;
    const int xcd = wg & 7;
    const int idx = wg >> 3;
    wg = (xcd < r ? xcd * (q + 1) : r * (q + 1) + (xcd - r) * q) + idx;
  }
  const int nt = wg % gx;
  const int mt = wg / gx;
  const int n0 = nt << 6;
  const int m0 = mt << 6;
  const int KSQ   = Fi >> 5;
  const int qsh   = __builtin_ctz(KSQ);
  const int qmask = KSQ - 1;
  const int KS    = NQ << qsh;

  const int laneoff = lane << 3;

  f32x16 acc = {};

#pragma unroll 2
  for (int ks = 0; ks < KS; ks++) {
    const int q   = ks >> qsh;
    const int ksl = ks & qmask;
    const u16* Ah = (q == 0) ? a0h : (q == 1 ? a1h : a2h);
    const u16* Al = (q == 0) ? a0l : (q == 1 ? a1l : a2l);
    const size_t abase = ((size_t)(mt * KSQ + ksl) << 2) * 512 + (size_t)((wm << 1) * 512) + laneoff;
    const bf16x8 aH0 = *(const bf16x8*)(Ah + abase);
    const bf16x8 aH1 = *(const bf16x8*)(Ah + abase + 512);
    const bf16x8 aL0 = *(const bf16x8*)(Al + abase);
    const bf16x8 aL1 = *(const bf16x8*)(Al + abase + 512);
    const size_t bbase = (((size_t)(nt * KS + ks) << 2) + (wn << 1)) * 512 + laneoff;
    const bf16x8 b0 = *(const bf16x8*)(packHi + bbase);
    const bf16x8 b1 = *(const bf16x8*)(packHi + bbase + 512);

    acc = __builtin_amdgcn_mfma_f32_32x32x16_bf16(aH0, b0, acc, 0, 0, 0);
    acc = __builtin_amdgcn_mfma_f32_32x32x16_bf16(aL0, b0, acc, 0, 0, 0);
    acc = __builtin_amdgcn_mfma_f32_32x32x16_bf16(aH1, b1, acc, 0, 0, 0);
    acc = __builtin_amdgcn_mfma_f32_32x32x16_bf16(aL1, b1, acc, 0, 0, 0);
    if (wflag) {
      const bf16x8 c0 = *(const bf16x8*)(packLo + bbase);
      const bf16x8 c1 = *(const bf16x8*)(packLo + bbase + 512);
      acc = __builtin_amdgcn_mfma_f32_32x32x16_bf16(aH0, c0, acc, 0, 0, 0);
      acc = __builtin_amdgcn_mfma_f32_32x32x16_bf16(aH1, c1, acc, 0, 0, 0);
    }
  }

  {
    const int ncol = n0 + (wn << 5) + (lane & 31);
    const int KSQo = Fo >> 5;
    int col = ncol;
    const void* bp = bias;
    size_t obase = 0;
    int FoOut = Fo;
    if (headSplit) {
      FoOut = 256;
      if (ncol >= 256) { col = ncol - 256; bp = bias2; obase = (size_t)N * 256; }
    }
    const float bv = wflag ? ((const float*)bp)[col]
                           : bf2f(((const u16*)bp)[col]);
#pragma unroll
    for (int r = 0; r < 16; r++) {
      const int m = m0 + (wm << 5) + (r & 3) + ((r >> 2) << 3) + ((lane >> 5) << 2);
      if (m < N) {
        float vv = acc[r] + bv;
        if (relu) vv = fmaxf(vv, 0.f);
        if (outF) outF[(size_t)m * Fo + ncol] = vv;
        if (outH) {
          u16 h = f2bf(vv);
          const size_t pi = apidx(m, ncol, KSQo);
          outH[pi] = h;
          outL[pi] = f2bf(vv - bf2f(h));
        }
        if (outB16) {
          const size_t o = obase + (size_t)m * FoOut + col;
          if (wflag) outB32[o] = vv;
          else       outB16[o] = f2bf(vv);
        }
      }
    }
  }
}

// ---------------- host (kernel launches ONLY) ----------------

static size_t align256(size_t x) { return (x + 255) & ~(size_t)255; }

extern "C" void kernel_launch(void* const* d_in, const int* in_sizes, int n_in,
                              void* d_out, int out_size, void* d_ws, size_t ws_size,
                              hipStream_t stream) {
  const void* v    = d_in[0];
  const void* ei   = d_in[1];
  const void* W1   = d_in[2];
  const void* b1   = d_in[3];
  const void* W2   = d_in[4];
  const void* b2   = d_in[5];
  const void* W3   = d_in[6];
  const void* b3   = d_in[7];
  const void* Wmu  = d_in[8];
  const void* bmu  = d_in[9];
  const void* Wstd = d_in[10];
  const void* bstd = d_in[11];
  (void)n_in; (void)ws_size;

  const int N = in_sizes[0] / 128;   // 10000
  const int E = in_sizes[1] / 2;     // 160000
  const size_t NP = ((size_t)N + 63) & ~(size_t)63;

  char* base = (char*)d_ws;
  size_t off = 0;
  auto carve = [&](size_t bytes) { void* p = base + off; off = align256(off + bytes); return p; };

  int*   eflag  = (int*)  carve(4);      // NOTE: eflag at flags[0], vflag flags[1]
  int*   vflag  = (int*)  carve(4);
  int*   rowi   = (int*)  carve((size_t)E * 4);
  int*   coli   = (int*)  carve((size_t)E * 4);
  float* deg    = (float*)carve((size_t)N * 4);
  float* dis    = (float*)carve((size_t)N * 4);
  int*   cnt    = (int*)  carve((size_t)N * 4);
  int*   colPtr = (int*)  carve((size_t)(N + 1) * 4);
  int*   cursor = (int*)  carve((size_t)N * 4);
  int2*  edges  = (int2*) carve((size_t)E * 8);

  u16* pW1h = (u16*)carve((size_t)384 * 128 * 2);
  u16* pW1l = (u16*)carve((size_t)384 * 128 * 2);
  u16* pW2h = (u16*)carve((size_t)384 * 256 * 2);
  u16* pW2l = (u16*)carve((size_t)384 * 256 * 2);
  u16* pW3h = (u16*)carve((size_t)768 * 512 * 2);
  u16* pW3l = (u16*)carve((size_t)768 * 512 * 2);
  u16* pHh  = (u16*)carve((size_t)2 * 512 * 256 * 2);
  u16* pHl  = (u16*)carve((size_t)2 * 512 * 256 * 2);

  float* Xf  = (float*)carve(NP * 256 * 4);
  u16*   Xh  = (u16*)  carve(NP * 256 * 2);
  u16*   Xl  = (u16*)  carve(NP * 256 * 2);
  float* Yf  = (float*)carve(NP * 128 * 4);
  u16*   Yh  = (u16*)  carve(NP * 512 * 2);
  u16*   Yl  = (u16*)  carve(NP * 512 * 2);
  float* t1f = (float*)carve(NP * 256 * 4);
  u16*   t1h = (u16*)  carve(NP * 256 * 2);
  u16*   t1l = (u16*)  carve(NP * 256 * 2);
  u16*   t2h = (u16*)  carve(NP * 256 * 2);
  u16*   t2l = (u16*)  carve(NP * 256 * 2);

  // 1) sentinel (safety: proves execution; overwritten by heads)
  k_sentinel<<<(out_size + 255) / 256, 256, 0, stream>>>((u16*)d_out, out_size);

  // 2) fused probes + zero
  const int zb = (N + 255) / 256;
  k_init<<<2 + zb, 256, 0, stream>>>((const unsigned*)v, 1024, vflag,
                                     (const unsigned*)ei, 2048, eflag,
                                     deg, cnt, N);

  // 3) fused weight packs + input convert (one dispatch)
  const int n4 = N * 128 / 4;
  const int c1 = 24, c2 = c1 + 48, c3 = c2 + 192, c4 = c3 + 64, c5 = c4 + 64;
  const int cTot = c5 + (n4 + 255) / 256;
  k_pack<<<cTot, 256, 0, stream>>>(W1, W2, W3, Wmu, Wstd,
                                   pW1h, pW1l, pW2h, pW2l, pW3h, pW3l, pHh, pHl,
                                   v, Xf, Xh, Xl, n4,
                                   eflag /* flags[0]=eflag, flags[1]=vflag */,
                                   c1, c2, c3, c4, c5);

  // 4) graph preprocessing (decode -> scan+dis -> place)
  k_decode<<<(E + 255) / 256, 256, 0, stream>>>(ei, eflag, E, N, rowi, coli, deg, cnt);
  k_scan<<<1, 1024, 0, stream>>>(cnt, colPtr, cursor, deg, dis, N);
  k_place<<<(E + 255) / 256, 256, 0, stream>>>(rowi, coli, dis, cursor, edges, E);

  const int gM = (N + 63) / 64;
  const int gP = (N + 3) / 4;

  // layer 1: Fi=128 -> Fo=128, X -> Y
  k_prop128<<<gP, 256, 0, stream>>>(Xf, nullptr, t1f, t1h, t1l, colPtr, edges, N, 1.f, 0.f);
  k_prop128<<<gP, 256, 0, stream>>>(t1f, Xf, nullptr, t2h, t2l, colPtr, edges, N, 2.f, -1.f);
  k_gemm_mfma<<<dim3(2, gM), 256, 0, stream>>>(Xh, Xl, t1h, t1l, t2h, t2l, pW1h, pW1l,
                                               b1, b1, vflag, N, 128, 3, 128,
                                               Yf, Yh, Yl, nullptr, nullptr, 1, 0);

  // layer 2: Fi=128 -> Fo=256, Y -> X
  k_prop128<<<gP, 256, 0, stream>>>(Yf, nullptr, t1f, t1h, t1l, colPtr, edges, N, 1.f, 0.f);
  k_prop128<<<gP, 256, 0, stream>>>(t1f, Yf, nullptr, t2h, t2l, colPtr, edges, N, 2.f, -1.f);
  k_gemm_mfma<<<dim3(4, gM), 256, 0, stream>>>(Yh, Yl, t1h, t1l, t2h, t2l, pW2h, pW2l,
                                               b2, b2, vflag, N, 128, 3, 256,
                                               Xf, Xh, Xl, nullptr, nullptr, 1, 0);

  // layer 3: Fi=256 -> Fo=512, X -> Y (packs only)
  k_prop256<<<gP, 256, 0, stream>>>(Xf, nullptr, t1f, t1h, t1l, colPtr, edges, N, 1.f, 0.f);
  k_prop256<<<gP, 256, 0, stream>>>(t1f, Xf, nullptr, t2h, t2l, colPtr, edges, N, 2.f, -1.f);
  k_gemm_mfma<<<dim3(8, gM), 256, 0, stream>>>(Xh, Xl, t1h, t1l, t2h, t2l, pW3h, pW3l,
                                               b3, b3, vflag, N, 256, 3, 512,
                                               nullptr, Yh, Yl, nullptr, nullptr, 1, 0);

  // fused heads
  k_gemm_mfma<<<dim3(8, gM), 256, 0, stream>>>(Yh, Yl, nullptr, nullptr, nullptr, nullptr,
                                               pHh, pHl, bmu, bstd, vflag, N, 512, 1, 512,
                                               nullptr, nullptr, nullptr,
                                               (u16*)d_out, (float*)d_out, 0, 1);
}